// Round 10
// baseline (454.422 us; speedup 1.0000x reference)
//
#include <hip/hip_runtime.h>
#include <stdint.h>

typedef unsigned short u16;

#define E_    8
#define DIM_  1024
#define HID_  2048
#define H2_   4096     // 2*HID
#define NTOK  8192     // B*T
#define RTOK  32       // tokens per router block
#define NT1   16       // K-tiles gemm1 (1024/64)
#define NT2   32       // K-tiles gemm2 (2048/64)

typedef __attribute__((ext_vector_type(8))) short bf16x8;
typedef __attribute__((ext_vector_type(4))) float f32x4;
typedef __attribute__((ext_vector_type(4))) unsigned int u32x4;

__device__ __forceinline__ u16 f2bf(float f) {
  uint32_t u = __builtin_bit_cast(uint32_t, f);
  uint32_t r = (u + 0x7FFFu + ((u >> 16) & 1u)) >> 16;
  return (u16)r;
}
__device__ __forceinline__ float bf2f(u16 u) {
  return __builtin_bit_cast(float, (uint32_t)u << 16);
}

__device__ __forceinline__ void gload16(const void* g, void* l) {
  __builtin_amdgcn_global_load_lds(
      (const __attribute__((address_space(1))) void*)g,
      (__attribute__((address_space(3))) void*)l, 16, 0, 0);
}

__device__ __forceinline__ uint32_t lds_addr(const void* p) {
  return (uint32_t)(uintptr_t)(const __attribute__((address_space(3))) void*)p;
}
// Opaque ds_read_b128: compiler sees no LDS read -> no auto waitcnt drains.
__device__ __forceinline__ bf16x8 ldsr(uint32_t a) {
  u32x4 r;
  asm volatile("ds_read_b128 %0, %1" : "=v"(r) : "v"(a));
  return __builtin_bit_cast(bf16x8, r);
}

#define MFMA_ __builtin_amdgcn_mfma_f32_16x16x32_bf16
#define SB0   __builtin_amdgcn_sched_barrier(0)

// ---------------- conversion kernels ----------------

__global__ void cvt_x(const float* __restrict__ x, u16* __restrict__ xb, int n8) {
  int i = blockIdx.x * blockDim.x + threadIdx.x;
  if (i >= n8) return;
  const float4* p = (const float4*)(x + (size_t)i * 8);
  float4 a = p[0], b = p[1];
  union { u16 u[8]; uint4 v; } r;
  r.u[0] = f2bf(a.x); r.u[1] = f2bf(a.y); r.u[2] = f2bf(a.z); r.u[3] = f2bf(a.w);
  r.u[4] = f2bf(b.x); r.u[5] = f2bf(b.y); r.u[6] = f2bf(b.z); r.u[7] = f2bf(b.w);
  *(uint4*)(xb + (size_t)i * 8) = r.v;
}

// src [e][R][C] fp32 -> dst [e][C][R] bf16 (64x64 tiles, 128B write granule)
__global__ void tconv(const float* __restrict__ src, u16* __restrict__ dst, int R, int C) {
  __shared__ float t[64][65];
  int e = blockIdx.z;
  int r0 = blockIdx.y * 64, c0 = blockIdx.x * 64;
  const float* s = src + (size_t)e * R * C;
  u16* d = dst + (size_t)e * R * C;
  int tid = threadIdx.x;
  int rr = tid >> 4, cc = (tid & 15) * 4;
#pragma unroll
  for (int p = 0; p < 4; ++p) {
    float4 v = *(const float4*)(s + (size_t)(r0 + p * 16 + rr) * C + c0 + cc);
    t[p * 16 + rr][cc + 0] = v.x; t[p * 16 + rr][cc + 1] = v.y;
    t[p * 16 + rr][cc + 2] = v.z; t[p * 16 + rr][cc + 3] = v.w;
  }
  __syncthreads();
  int cr = tid >> 3, rc = (tid & 7) * 8;
#pragma unroll
  for (int p = 0; p < 2; ++p) {
    union { u16 u[8]; uint4 v; } w;
#pragma unroll
    for (int j = 0; j < 8; ++j) w.u[j] = f2bf(t[rc + j][p * 32 + cr]);
    *(uint4*)(d + (size_t)(c0 + p * 32 + cr) * R + r0 + rc) = w.v;
  }
}

// ---------------- router (block-aggregated, low-contention atomics) ----------------

__global__ void router(const float* __restrict__ x, const float* __restrict__ rw,
                       const float* __restrict__ rb, int* __restrict__ counts,
                       int* __restrict__ btok, float* __restrict__ bw,
                       int* __restrict__ tokrec) {
  __shared__ float srw[E_ * DIM_];
  __shared__ float sb[E_];
  __shared__ int   hcnt[E_], hbase[E_];
  __shared__ int   te[RTOK * 2];
  __shared__ float twt[RTOK * 2];
  __shared__ int   tloc[RTOK * 2];

  int tid = threadIdx.x;
  for (int i = tid; i < E_ * DIM_ / 4; i += 256)
    ((float4*)srw)[i] = ((const float4*)rw)[i];
  if (tid < E_) { sb[tid] = rb[tid]; hcnt[tid] = 0; }
  __syncthreads();

  int wid = tid >> 6, lane = tid & 63;
#pragma unroll
  for (int s = 0; s < RTOK / 4; ++s) {
    int lt = wid * (RTOK / 4) + s;
    int t = blockIdx.x * RTOK + lt;
    const float* xt = x + (size_t)t * DIM_;
    float acc[8] = {0.f, 0.f, 0.f, 0.f, 0.f, 0.f, 0.f, 0.f};
#pragma unroll
    for (int it = 0; it < 4; ++it) {
      int d = it * 256 + lane * 4;
      float4 xv = *(const float4*)(xt + d);
#pragma unroll
      for (int e = 0; e < 8; ++e) {
        float4 rv = *(const float4*)(&srw[e * DIM_ + d]);
        acc[e] += xv.x * rv.x + xv.y * rv.y + xv.z * rv.z + xv.w * rv.w;
      }
    }
#pragma unroll
    for (int e = 0; e < 8; ++e)
#pragma unroll
      for (int off = 32; off; off >>= 1)
        acc[e] += __shfl_xor(acc[e], off, 64);
    if (lane == 0) {
      float v[8];
#pragma unroll
      for (int e = 0; e < 8; ++e) v[e] = acc[e] + sb[e];
      int i0 = 0;
#pragma unroll
      for (int e = 1; e < 8; ++e) if (v[e] > v[i0]) i0 = e;
      int i1 = (i0 == 0) ? 1 : 0;
#pragma unroll
      for (int e = 0; e < 8; ++e) if (e != i0 && v[e] > v[i1]) i1 = e;
      float w0 = 1.f / (1.f + expf(v[i1] - v[i0]));
      float w1 = 1.f - w0;
      int l0 = atomicAdd(&hcnt[i0], 1);
      int l1 = atomicAdd(&hcnt[i1], 1);
      te[lt * 2 + 0] = i0; twt[lt * 2 + 0] = w0; tloc[lt * 2 + 0] = l0;
      te[lt * 2 + 1] = i1; twt[lt * 2 + 1] = w1; tloc[lt * 2 + 1] = l1;
    }
  }
  __syncthreads();
  if (tid < E_) hbase[tid] = atomicAdd(&counts[tid], hcnt[tid]);
  __syncthreads();
  if (tid < RTOK * 2) {
    int e = te[tid];
    int p = hbase[e] + tloc[tid];
    int t = blockIdx.x * RTOK + (tid >> 1);
    btok[e * NTOK + p] = t;
    bw[e * NTOK + p] = twt[tid];
    tokrec[t * 2 + (tid & 1)] = (e << 13) | p;
  }
}

// ============ 256x256 8-phase GEMM core, counted vmcnt(8) ============
// 512 thr = 8 waves (2M x 4N), BK=64. LDS/buf: {A-lo, A-hi, B-lo, B-hi},
// each region [256 rows][32 K] bf16 = 16 KB; 2 buffers = 128 KiB.
// Phase (ks,np): 16 MFMA on K-half ks, n-pair np. Stage map (tile t):
//   ph0 -> A-hi(t+1) [buf o: readers done end of t-1]
//   ph1 -> B-hi(t+1) [same]
//   ph2 -> A-lo(t+2) [buf c: A-lo(t) reads done ph0/ph1, 2 barriers ago]
//   ph3 -> B-lo(t+2) [same]
// vmcnt(8) before end-barrier of ph1 & ph3: waits only loads issued 5-6
// phases earlier; 8 loads (2 K-tiles of lookahead) always in flight.
// Seg swizzle s(row) = (row ^ row>>2)&3: read fo = (lhi^s)*16 (2-way banks,
// free); stage pre-swizzles the GLOBAL source, LDS dest stays lane-linear.

#define STGA(bb, kh, tt, NTt)                                               \
  { int tc_ = (tt) < (NTt) ? (tt) : (NTt) - 1;                              \
    gload16(pA[0] + tc_ * 64 + (kh) * 32,                                   \
            sm + (bb) * 32768 + (kh) * 8192 + tid * 8);                     \
    gload16(pA[1] + tc_ * 64 + (kh) * 32,                                   \
            sm + (bb) * 32768 + (kh) * 8192 + 4096 + tid * 8); }
#define STGB(bb, kh, tt, NTt)                                               \
  { int tc_ = (tt) < (NTt) ? (tt) : (NTt) - 1;                              \
    gload16(pB[0] + tc_ * 64 + (kh) * 32,                                   \
            sm + (bb) * 32768 + 16384 + (kh) * 8192 + tid * 8);             \
    gload16(pB[1] + tc_ * 64 + (kh) * 32,                                   \
            sm + (bb) * 32768 + 16384 + (kh) * 8192 + 4096 + tid * 8); }
#define FENCE asm volatile("" ::: "memory")

template <int NTt>
__device__ __forceinline__ void kloop(u16* __restrict__ sm,
                                      const u16* const* pA, const u16* const* pB,
                                      int tid, int wr, int wc, int l15, int lhi,
                                      f32x4 (&acc)[8][4]) {
  // prologue: A-lo(0) B-lo(0) A-hi(0) B-hi(0) A-lo(1) B-lo(1)  (12 loads)
  STGA(0, 0, 0, NTt); STGB(0, 0, 0, NTt);
  STGA(0, 1, 0, NTt); STGB(0, 1, 0, NTt);
  STGA(1, 0, 1, NTt); STGB(1, 0, 1, NTt);
  asm volatile("s_waitcnt vmcnt(8)" ::: "memory");   // A-lo(0),B-lo(0) landed
  __builtin_amdgcn_s_barrier();

  const uint32_t fo = (uint32_t)(((lhi ^ l15 ^ (l15 >> 2)) & 3) * 16);
  const uint32_t base = lds_addr(sm);
  const uint32_t arow = (uint32_t)((wr * 128 + l15) * 64);
  const uint32_t brow = (uint32_t)((wc * 64 + l15) * 64);

  for (int t = 0; t < NTt; ++t) {
    int c = t & 1, o = c ^ 1;
    bf16x8 a[8];
#pragma unroll
    for (int ks = 0; ks < 2; ++ks) {
      uint32_t aR = base + (uint32_t)(c * 65536 + ks * 16384) + arow + fo;
      uint32_t bR = base + (uint32_t)(c * 65536 + 32768 + ks * 16384) + brow + fo;

      // ---- phase (ks, np=0): 10 ds_reads, 1 stage, 16 MFMA ----
      bf16x8 b0 = ldsr(bR);
      bf16x8 b1 = ldsr(bR + 1024);
#pragma unroll
      for (int m = 0; m < 8; ++m) a[m] = ldsr(aR + (uint32_t)(m * 1024));
      if (ks == 0) STGA(o, 1, t + 1, NTt)       // A-hi(t+1)
      else         STGA(c, 0, t + 2, NTt)       // A-lo(t+2)
      FENCE;
      __builtin_amdgcn_s_barrier();
      asm volatile("s_waitcnt lgkmcnt(0)");
      SB0;
      __builtin_amdgcn_s_setprio(1);
#pragma unroll
      for (int m = 0; m < 8; ++m) {
        acc[m][0] = MFMA_(a[m], b0, acc[m][0], 0, 0, 0);
        acc[m][1] = MFMA_(a[m], b1, acc[m][1], 0, 0, 0);
      }
      __builtin_amdgcn_s_setprio(0);
      __builtin_amdgcn_s_barrier();

      // ---- phase (ks, np=1): 2 ds_reads, 1 stage, 16 MFMA ----
      bf16x8 b2 = ldsr(bR + 2048);
      bf16x8 b3 = ldsr(bR + 3072);
      if (ks == 0) STGB(o, 1, t + 1, NTt)       // B-hi(t+1)
      else         STGB(c, 0, t + 2, NTt)       // B-lo(t+2)
      FENCE;
      __builtin_amdgcn_s_barrier();
      asm volatile("s_waitcnt lgkmcnt(0)");
      SB0;
      __builtin_amdgcn_s_setprio(1);
#pragma unroll
      for (int m = 0; m < 8; ++m) {
        acc[m][2] = MFMA_(a[m], b2, acc[m][2], 0, 0, 0);
        acc[m][3] = MFMA_(a[m], b3, acc[m][3], 0, 0, 0);
      }
      __builtin_amdgcn_s_setprio(0);
      asm volatile("s_waitcnt vmcnt(8)" ::: "memory");  // counted, never 0
      __builtin_amdgcn_s_barrier();
    }
  }
  asm volatile("s_waitcnt vmcnt(0)" ::: "memory");
}

// ---------------- GEMM1: gathered x @ W1 -> swiglu -> hb ----------------

__launch_bounds__(512, 2)
__global__ void gemm1(const u16* __restrict__ xb, const u16* __restrict__ w1t,
                      const float* __restrict__ b1, const int* __restrict__ counts,
                      const int* __restrict__ btok, u16* __restrict__ hb) {
  int e = blockIdx.z, mblk = blockIdx.y, nblk = blockIdx.x;
  int cnt = counts[e];
  if (mblk * 256 >= cnt) return;
  int base = 0;
#pragma unroll
  for (int i = 0; i < 8; ++i) base += (i < e) ? counts[i] : 0;

  __shared__ u16 sm[65536];
  __shared__ int sTok[256];

  int tid = threadIdx.x, wid = tid >> 6, lane = tid & 63;
  if (tid < 256) {
    int gr = mblk * 256 + tid;
    sTok[tid] = (gr < cnt) ? btok[e * NTOK + gr] : btok[e * NTOK];
  }
  __syncthreads();

  int wr = wid >> 2, wc = wid & 3;
  int l15 = lane & 15, lhi = lane >> 4;
  // stage-side pre-swizzled global seg offset (u16 units)
  int sw = (((tid & 3) ^ ((tid >> 2) & 3) ^ ((tid >> 4) & 3)) & 3) * 8;
  int r0 = tid >> 2, r1 = r0 + 128;

  const u16* pA[2];
  const u16* pB[2];
  const size_t w1e = (size_t)e * H2_ * DIM_;
  pA[0] = xb + (size_t)sTok[r0] * DIM_ + sw;
  pA[1] = xb + (size_t)sTok[r1] * DIM_ + sw;
  {
    int g0 = nblk * 128 + (r0 >> 6) * 32 + (r0 & 31) + ((r0 >> 5) & 1) * 2048;
    int g1 = nblk * 128 + (r1 >> 6) * 32 + (r1 & 31) + ((r1 >> 5) & 1) * 2048;
    pB[0] = w1t + w1e + (size_t)g0 * DIM_ + sw;
    pB[1] = w1t + w1e + (size_t)g1 * DIM_ + sw;
  }

  f32x4 acc[8][4] = {};
  kloop<NT1>(sm, pA, pB, tid, wr, wc, l15, lhi, acc);

#pragma unroll
  for (int q = 0; q < 2; ++q) {
    int oc = nblk * 128 + wc * 32 + q * 16 + l15;
    float bb1 = b1[e * H2_ + oc];
    float bb2 = b1[e * H2_ + oc + HID_];
#pragma unroll
    for (int m = 0; m < 8; ++m) {
#pragma unroll
      for (int j = 0; j < 4; ++j) {
        int rt = wr * 128 + m * 16 + lhi * 4 + j;
        int gr = mblk * 256 + rt;
        if (gr < cnt) {
          float h1 = acc[m][q][j] + bb1;
          float h2 = acc[m][q + 2][j] + bb2;
          float s = (h1 / (1.f + __expf(-h1))) * h2;
          hb[(size_t)(base + gr) * HID_ + oc] = f2bf(s);
        }
      }
    }
  }
}

// ---------------- GEMM2: hb @ W2 -> w*(y+b2) stored bf16 to ybuf ----------------

__launch_bounds__(512, 2)
__global__ void gemm2(const u16* __restrict__ hb, const u16* __restrict__ w2t,
                      const float* __restrict__ b2, const int* __restrict__ counts,
                      const float* __restrict__ bw, u16* __restrict__ ybuf) {
  int e = blockIdx.z, mblk = blockIdx.y, nblk = blockIdx.x;
  int cnt = counts[e];
  if (mblk * 256 >= cnt) return;
  int base = 0;
#pragma unroll
  for (int i = 0; i < 8; ++i) base += (i < e) ? counts[i] : 0;

  __shared__ u16 sm[65536];
  __shared__ float sW[256];

  int tid = threadIdx.x, wid = tid >> 6, lane = tid & 63;
  if (tid < 256) {
    int gr = mblk * 256 + tid;
    sW[tid] = (gr < cnt) ? bw[e * NTOK + gr] : 0.f;
  }
  __syncthreads();

  int wr = wid >> 2, wc = wid & 3;
  int l15 = lane & 15, lhi = lane >> 4;
  int sw = (((tid & 3) ^ ((tid >> 2) & 3) ^ ((tid >> 4) & 3)) & 3) * 8;
  int r0 = tid >> 2, r1 = r0 + 128;

  const u16* pA[2];
  const u16* pB[2];
  pA[0] = hb + (size_t)(base + mblk * 256 + r0) * HID_ + sw;
  pA[1] = hb + (size_t)(base + mblk * 256 + r1) * HID_ + sw;
  pB[0] = w2t + (size_t)e * DIM_ * HID_ + (size_t)(nblk * 256 + r0) * HID_ + sw;
  pB[1] = w2t + (size_t)e * DIM_ * HID_ + (size_t)(nblk * 256 + r1) * HID_ + sw;

  f32x4 acc[8][4] = {};
  kloop<NT2>(sm, pA, pB, tid, wr, wc, l15, lhi, acc);

#pragma unroll
  for (int q = 0; q < 4; ++q) {
    int col = nblk * 256 + wc * 64 + q * 16 + l15;
    float bb = b2[e * DIM_ + col];
#pragma unroll
    for (int m = 0; m < 8; ++m) {
#pragma unroll
      for (int j = 0; j < 4; ++j) {
        int rt = wr * 128 + m * 16 + lhi * 4 + j;
        int gr = mblk * 256 + rt;
        if (gr < cnt)
          ybuf[(size_t)(base + gr) * DIM_ + col] = f2bf(sW[rt] * (acc[m][q][j] + bb));
      }
    }
  }
}

// ---------------- combine: out[t] = ybuf[slot(t,0)] + ybuf[slot(t,1)] ----------------

__global__ void combine(const u16* __restrict__ ybuf, const int* __restrict__ tokrec,
                        const int* __restrict__ counts, float* __restrict__ out) {
  __shared__ int sbase[8];
  int tid = threadIdx.x;
  if (tid == 0) {
    int b = 0;
#pragma unroll
    for (int e = 0; e < 8; ++e) { sbase[e] = b; b += counts[e]; }
  }
  __syncthreads();
  int t = blockIdx.x;
  int r0 = tokrec[t * 2 + 0], r1 = tokrec[t * 2 + 1];
  size_t s0 = (size_t)(sbase[r0 >> 13] + (r0 & 8191)) * DIM_;
  size_t s1 = (size_t)(sbase[r1 >> 13] + (r1 & 8191)) * DIM_;
  int c = tid * 4;
  ushort4 a = *(const ushort4*)(ybuf + s0 + c);
  ushort4 b = *(const ushort4*)(ybuf + s1 + c);
  float4 o;
  o.x = bf2f(a.x) + bf2f(b.x);
  o.y = bf2f(a.y) + bf2f(b.y);
  o.z = bf2f(a.z) + bf2f(b.z);
  o.w = bf2f(a.w) + bf2f(b.w);
  *(float4*)(out + (size_t)t * DIM_ + c) = o;
}

// ---------------- launch ----------------

extern "C" void kernel_launch(void* const* d_in, const int* in_sizes, int n_in,
                              void* d_out, int out_size, void* d_ws, size_t ws_size,
                              hipStream_t stream) {
  const float* x  = (const float*)d_in[0];
  const float* rw = (const float*)d_in[1];
  const float* rb = (const float*)d_in[2];
  const float* W1 = (const float*)d_in[3];
  const float* b1 = (const float*)d_in[4];
  const float* W2 = (const float*)d_in[5];
  const float* b2 = (const float*)d_in[6];
  float* out = (float*)d_out;

  char* ws = (char*)d_ws;
  int*   counts = (int*)ws;                         // 32 B (256 pad)
  int*   btok   = (int*)(ws + 256);                 // 256 KB
  float* bw     = (float*)(ws + 256 + 262144);      // 256 KB
  int*   tokrec = (int*)(ws + 256 + 524288);        // 64 KB
  u16* xb  = (u16*)(ws + (1u << 20));               // 16 MB
  u16* w1t = xb  + (size_t)NTOK * DIM_;             // 64 MB
  u16* w2t = w1t + (size_t)E_ * H2_ * DIM_;         // 32 MB
  u16* hb  = w2t + (size_t)E_ * DIM_ * HID_;        // (16384+256)*2048*2 B
  u16* ybuf = w1t;  // alias: w1t dead after gemm1

  hipMemsetAsync(counts, 0, 8 * sizeof(int), stream);

  cvt_x<<<(NTOK * DIM_ / 8 + 255) / 256, 256, 0, stream>>>(x, xb, NTOK * DIM_ / 8);
  tconv<<<dim3(H2_ / 64, DIM_ / 64, E_), 256, 0, stream>>>(W1, w1t, DIM_, H2_);
  tconv<<<dim3(DIM_ / 64, HID_ / 64, E_), 256, 0, stream>>>(W2, w2t, HID_, DIM_);
  router<<<NTOK / RTOK, 256, 0, stream>>>(x, rw, rb, counts, btok, bw, tokrec);

  gemm1<<<dim3(H2_ / 256, NTOK / 256, E_), 512, 0, stream>>>(xb, w1t, b1, counts, btok, hb);
  gemm2<<<dim3(DIM_ / 256, NTOK / 256, E_), 512, 0, stream>>>(hb, w2t, b2, counts, bw, ybuf);
  combine<<<NTOK, 256, 0, stream>>>(ybuf, tokrec, counts, out);
}

// Round 11
// 381.052 us; speedup vs baseline: 1.1925x; 1.1925x over previous
//
#include <hip/hip_runtime.h>
#include <stdint.h>

typedef unsigned short u16;

#define E_    8
#define DIM_  1024
#define HID_  2048
#define H2_   4096     // 2*HID
#define NTOK  8192     // B*T

typedef __attribute__((ext_vector_type(8))) short bf16x8;
typedef __attribute__((ext_vector_type(4))) float f32x4;

__device__ __forceinline__ u16 f2bf(float f) {
  uint32_t u = __builtin_bit_cast(uint32_t, f);
  uint32_t r = (u + 0x7FFFu + ((u >> 16) & 1u)) >> 16;
  return (u16)r;
}
__device__ __forceinline__ float bf2f(u16 u) {
  return __builtin_bit_cast(float, (uint32_t)u << 16);
}

__device__ __forceinline__ void gload16(const void* g, void* l) {
  __builtin_amdgcn_global_load_lds(
      (const __attribute__((address_space(1))) void*)g,
      (__attribute__((address_space(3))) void*)l, 16, 0, 0);
}

// ---------------- weight transpose (64x64 tiles, 128B write granule) ----------------

__global__ void tconv(const float* __restrict__ src, u16* __restrict__ dst, int R, int C) {
  __shared__ float t[64][65];
  int e = blockIdx.z;
  int r0 = blockIdx.y * 64, c0 = blockIdx.x * 64;
  const float* s = src + (size_t)e * R * C;
  u16* d = dst + (size_t)e * R * C;
  int tid = threadIdx.x;
  int rr = tid >> 4, cc = (tid & 15) * 4;
#pragma unroll
  for (int p = 0; p < 4; ++p) {
    float4 v = *(const float4*)(s + (size_t)(r0 + p * 16 + rr) * C + c0 + cc);
    t[p * 16 + rr][cc + 0] = v.x; t[p * 16 + rr][cc + 1] = v.y;
    t[p * 16 + rr][cc + 2] = v.z; t[p * 16 + rr][cc + 3] = v.w;
  }
  __syncthreads();
  int cr = tid >> 3, rc = (tid & 7) * 8;
#pragma unroll
  for (int p = 0; p < 2; ++p) {
    union { u16 u[8]; uint4 v; } w;
#pragma unroll
    for (int j = 0; j < 8; ++j) w.u[j] = f2bf(t[rc + j][p * 32 + cr]);
    *(uint4*)(d + (size_t)(c0 + p * 32 + cr) * R + r0 + rc) = w.v;
  }
}

// ---------------- routerA: logits + top2 + x->bf16, per-block counts ----------------
// 1024 blocks x 256 thr, 8 tokens/block (2 per wave). No global atomics.

__global__ void routerA(const float* __restrict__ x, const float* __restrict__ rw,
                        const float* __restrict__ rb, u16* __restrict__ xb,
                        int* __restrict__ gcnt, int2* __restrict__ te_l,
                        float2* __restrict__ tw) {
  __shared__ float srw[E_ * DIM_];   // 32 KB
  __shared__ float sb[E_];
  __shared__ int   hcnt[E_];

  int tid = threadIdx.x;
  for (int i = tid; i < E_ * DIM_ / 4; i += 256)
    ((float4*)srw)[i] = ((const float4*)rw)[i];
  if (tid < E_) { sb[tid] = rb[tid]; hcnt[tid] = 0; }
  __syncthreads();

  int wid = tid >> 6, lane = tid & 63;
#pragma unroll
  for (int s = 0; s < 2; ++s) {
    int t = blockIdx.x * 8 + wid * 2 + s;
    const float* xt = x + (size_t)t * DIM_;
    float acc[8] = {0.f, 0.f, 0.f, 0.f, 0.f, 0.f, 0.f, 0.f};
#pragma unroll
    for (int it = 0; it < 4; ++it) {
      int d = it * 256 + lane * 4;
      float4 xv = *(const float4*)(xt + d);
      ushort4 xo;
      xo.x = f2bf(xv.x); xo.y = f2bf(xv.y); xo.z = f2bf(xv.z); xo.w = f2bf(xv.w);
      *(ushort4*)(xb + (size_t)t * DIM_ + d) = xo;   // fused x -> bf16
#pragma unroll
      for (int e = 0; e < 8; ++e) {
        float4 rv = *(const float4*)(&srw[e * DIM_ + d]);
        acc[e] += xv.x * rv.x + xv.y * rv.y + xv.z * rv.z + xv.w * rv.w;
      }
    }
#pragma unroll
    for (int e = 0; e < 8; ++e)
#pragma unroll
      for (int off = 32; off; off >>= 1)
        acc[e] += __shfl_xor(acc[e], off, 64);
    if (lane == 0) {
      float v[8];
#pragma unroll
      for (int e = 0; e < 8; ++e) v[e] = acc[e] + sb[e];
      int i0 = 0;
#pragma unroll
      for (int e = 1; e < 8; ++e) if (v[e] > v[i0]) i0 = e;
      int i1 = (i0 == 0) ? 1 : 0;
#pragma unroll
      for (int e = 0; e < 8; ++e) if (e != i0 && v[e] > v[i1]) i1 = e;
      float w0 = 1.f / (1.f + expf(v[i1] - v[i0]));
      int l0 = atomicAdd(&hcnt[i0], 1);   // LDS atomics only
      int l1 = atomicAdd(&hcnt[i1], 1);
      te_l[t] = make_int2((i0 << 8) | l0, (i1 << 8) | l1);
      tw[t] = make_float2(w0, 1.f - w0);
    }
  }
  __syncthreads();
  if (tid < E_) gcnt[tid * 1024 + blockIdx.x] = hcnt[tid];
}

// ---------------- routerB: per-expert exclusive prefix over 1024 blocks ----------------

__global__ void routerB(const int* __restrict__ gcnt, int* __restrict__ base_blk,
                        int* __restrict__ counts) {
  __shared__ int part[256];
  int tid = threadIdx.x;
#pragma unroll
  for (int e = 0; e < 8; ++e) {
    int4 v = *(const int4*)(gcnt + e * 1024 + tid * 4);
    int s = v.x + v.y + v.z + v.w;
    part[tid] = s;
    __syncthreads();
    for (int off = 1; off < 256; off <<= 1) {
      int o = (tid >= off) ? part[tid - off] : 0;
      __syncthreads();
      part[tid] += o;
      __syncthreads();
    }
    int ex = part[tid] - s;       // exclusive prefix for this thread's 4 blocks
    int tot = part[255];
    int4 b;
    b.x = ex; b.y = ex + v.x; b.z = ex + v.x + v.y; b.w = ex + v.x + v.y + v.z;
    *(int4*)(base_blk + e * 1024 + tid * 4) = b;
    if (tid == 0) counts[e] = tot;
    __syncthreads();
  }
}

// ---------------- routerC: scatter bucket entries ----------------

__global__ void routerC(const int2* __restrict__ te_l, const float2* __restrict__ tw,
                        const int* __restrict__ base_blk, int* __restrict__ btok,
                        float* __restrict__ bw, int* __restrict__ tokrec) {
  int t = blockIdx.x * 256 + threadIdx.x;   // 8192 tokens
  int2 r = te_l[t];
  float2 w = tw[t];
  int b = t >> 3;
  int e0 = r.x >> 8, l0 = r.x & 255;
  int e1 = r.y >> 8, l1 = r.y & 255;
  int p0 = base_blk[e0 * 1024 + b] + l0;
  int p1 = base_blk[e1 * 1024 + b] + l1;
  btok[e0 * NTOK + p0] = t; bw[e0 * NTOK + p0] = w.x; tokrec[t * 2 + 0] = (e0 << 13) | p0;
  btok[e1 * NTOK + p1] = t; bw[e1 * NTOK + p1] = w.y; tokrec[t * 2 + 1] = (e1 << 13) | p1;
}

// ---------------- GEMM1: gathered x @ W1 -> swiglu -> hb (R9-proven) ----------------

__launch_bounds__(256, 4)
__global__ void gemm1(const u16* __restrict__ xb, const u16* __restrict__ w1t,
                      const float* __restrict__ b1, const int* __restrict__ counts,
                      const int* __restrict__ btok, u16* __restrict__ hb) {
  int e = blockIdx.z, mblk = blockIdx.y, nblk = blockIdx.x;
  int cnt = counts[e];
  if (mblk * 128 >= cnt) return;
  int base = 0;
#pragma unroll
  for (int i = 0; i < 8; ++i) base += (i < e) ? counts[i] : 0;

  __shared__ u16 lA[128 * 64];
  __shared__ u16 lB[128 * 64];
  __shared__ int sTok[128];

  int tid = threadIdx.x, wid = tid >> 6, lane = tid & 63;
  if (tid < 128) {
    int gr = mblk * 128 + tid;
    sTok[tid] = (gr < cnt) ? btok[e * NTOK + gr] : btok[e * NTOK];
  }
  __syncthreads();

  f32x4 acc[4][4] = {};
  int wr = wid >> 1, wc = wid & 1;
  int l15 = lane & 15, lhi = lane >> 4;
  const size_t w1e = (size_t)e * H2_ * DIM_;

  int segsw = ((lane & 7) ^ ((lane >> 3) & 7)) * 8;
  const u16* gA[4];
  const u16* gB[4];
#pragma unroll
  for (int i = 0; i < 4; ++i) {
    int r = wid * 32 + i * 8 + (lane >> 3);
    gA[i] = xb + (size_t)sTok[r] * DIM_ + segsw;
    int gcol = nblk * 64 + (r >> 6) * 32 + (r & 31) + ((r >> 5) & 1) * 2048;
    gB[i] = w1t + w1e + (size_t)gcol * DIM_ + segsw;
  }
  int rxor = (l15 & 7) * 8;

  for (int kt = 0; kt < DIM_ / 64; ++kt) {
#pragma unroll
    for (int i = 0; i < 4; ++i)
      gload16(gA[i] + kt * 64, &lA[(wid * 32 + i * 8) * 64]);
#pragma unroll
    for (int i = 0; i < 4; ++i)
      gload16(gB[i] + kt * 64, &lB[(wid * 32 + i * 8) * 64]);
    __syncthreads();
#pragma unroll
    for (int ks = 0; ks < 2; ++ks) {
      int segrd = ((ks * 4 + lhi) * 8) ^ rxor;
      bf16x8 a[4], b[4];
#pragma unroll
      for (int m = 0; m < 4; ++m)
        a[m] = *(const bf16x8*)&lA[(wr * 64 + m * 16 + l15) * 64 + segrd];
#pragma unroll
      for (int n = 0; n < 4; ++n)
        b[n] = *(const bf16x8*)&lB[(wc * 64 + n * 16 + l15) * 64 + segrd];
#pragma unroll
      for (int m = 0; m < 4; ++m)
#pragma unroll
        for (int n = 0; n < 4; ++n)
          acc[m][n] = __builtin_amdgcn_mfma_f32_16x16x32_bf16(a[m], b[n], acc[m][n], 0, 0, 0);
    }
    __syncthreads();
  }

#pragma unroll
  for (int n = 0; n < 2; ++n) {
    int outcol = nblk * 64 + wc * 32 + n * 16 + l15;
    float bb1 = b1[e * H2_ + outcol];
    float bb2 = b1[e * H2_ + outcol + HID_];
#pragma unroll
    for (int m = 0; m < 4; ++m) {
#pragma unroll
      for (int j = 0; j < 4; ++j) {
        int rt = wr * 64 + m * 16 + lhi * 4 + j;
        int gr = mblk * 128 + rt;
        if (gr < cnt) {
          float h1 = acc[m][n][j] + bb1;
          float h2 = acc[m][n + 2][j] + bb2;
          float s = (h1 / (1.f + __expf(-h1))) * h2;
          hb[(size_t)(base + gr) * HID_ + outcol] = f2bf(s);
        }
      }
    }
  }
}

// ---------------- GEMM2: hb @ W2 -> w*(y+b2) stored bf16 to ybuf ----------------

__launch_bounds__(256, 4)
__global__ void gemm2(const u16* __restrict__ hb, const u16* __restrict__ w2t,
                      const float* __restrict__ b2, const int* __restrict__ counts,
                      const float* __restrict__ bw, u16* __restrict__ ybuf) {
  int e = blockIdx.z, mblk = blockIdx.y, nblk = blockIdx.x;
  int cnt = counts[e];
  if (mblk * 128 >= cnt) return;
  int base = 0;
#pragma unroll
  for (int i = 0; i < 8; ++i) base += (i < e) ? counts[i] : 0;

  __shared__ u16 lA[128 * 64];
  __shared__ u16 lB[128 * 64];
  __shared__ float sW[128];

  int tid = threadIdx.x, wid = tid >> 6, lane = tid & 63;
  if (tid < 128) {
    int gr = mblk * 128 + tid;
    sW[tid] = (gr < cnt) ? bw[e * NTOK + gr] : 0.f;
  }
  __syncthreads();

  f32x4 acc[4][4] = {};
  int wr = wid >> 1, wc = wid & 1;
  int l15 = lane & 15, lhi = lane >> 4;

  int segsw = ((lane & 7) ^ ((lane >> 3) & 7)) * 8;
  const u16* gA[4];
  const u16* gB[4];
#pragma unroll
  for (int i = 0; i < 4; ++i) {
    int r = wid * 32 + i * 8 + (lane >> 3);
    gA[i] = hb + (size_t)(base + mblk * 128 + r) * HID_ + segsw;
    gB[i] = w2t + (size_t)e * DIM_ * HID_ + (size_t)(nblk * 128 + r) * HID_ + segsw;
  }
  int rxor = (l15 & 7) * 8;

  for (int kt = 0; kt < HID_ / 64; ++kt) {
#pragma unroll
    for (int i = 0; i < 4; ++i) {
      gload16(gA[i] + kt * 64, &lA[(wid * 32 + i * 8) * 64]);
      gload16(gB[i] + kt * 64, &lB[(wid * 32 + i * 8) * 64]);
    }
    __syncthreads();
#pragma unroll
    for (int ks = 0; ks < 2; ++ks) {
      int segrd = ((ks * 4 + lhi) * 8) ^ rxor;
      bf16x8 a[4], b[4];
#pragma unroll
      for (int m = 0; m < 4; ++m)
        a[m] = *(const bf16x8*)&lA[(wr * 64 + m * 16 + l15) * 64 + segrd];
#pragma unroll
      for (int n = 0; n < 4; ++n)
        b[n] = *(const bf16x8*)&lB[(wc * 64 + n * 16 + l15) * 64 + segrd];
#pragma unroll
      for (int m = 0; m < 4; ++m)
#pragma unroll
        for (int n = 0; n < 4; ++n)
          acc[m][n] = __builtin_amdgcn_mfma_f32_16x16x32_bf16(a[m], b[n], acc[m][n], 0, 0, 0);
    }
    __syncthreads();
  }

#pragma unroll
  for (int n = 0; n < 4; ++n) {
    int col = nblk * 128 + wc * 64 + n * 16 + l15;
    float bb = b2[e * DIM_ + col];
#pragma unroll
    for (int m = 0; m < 4; ++m) {
#pragma unroll
      for (int j = 0; j < 4; ++j) {
        int rt = wr * 64 + m * 16 + lhi * 4 + j;
        int gr = mblk * 128 + rt;
        if (gr < cnt)
          ybuf[(size_t)(base + gr) * DIM_ + col] = f2bf(sW[rt] * (acc[m][n][j] + bb));
      }
    }
  }
}

// ---------------- combine: out[t] = ybuf[slot(t,0)] + ybuf[slot(t,1)] ----------------

__global__ void combine(const u16* __restrict__ ybuf, const int* __restrict__ tokrec,
                        const int* __restrict__ counts, float* __restrict__ out) {
  __shared__ int sbase[8];
  int tid = threadIdx.x;
  if (tid == 0) {
    int b = 0;
#pragma unroll
    for (int e = 0; e < 8; ++e) { sbase[e] = b; b += counts[e]; }
  }
  __syncthreads();
  int t = blockIdx.x;
  int r0 = tokrec[t * 2 + 0], r1 = tokrec[t * 2 + 1];
  size_t s0 = (size_t)(sbase[r0 >> 13] + (r0 & 8191)) * DIM_;
  size_t s1 = (size_t)(sbase[r1 >> 13] + (r1 & 8191)) * DIM_;
  int c = tid * 4;
  ushort4 a = *(const ushort4*)(ybuf + s0 + c);
  ushort4 b = *(const ushort4*)(ybuf + s1 + c);
  float4 o;
  o.x = bf2f(a.x) + bf2f(b.x);
  o.y = bf2f(a.y) + bf2f(b.y);
  o.z = bf2f(a.z) + bf2f(b.z);
  o.w = bf2f(a.w) + bf2f(b.w);
  *(float4*)(out + (size_t)t * DIM_ + c) = o;
}

// ---------------- launch ----------------

extern "C" void kernel_launch(void* const* d_in, const int* in_sizes, int n_in,
                              void* d_out, int out_size, void* d_ws, size_t ws_size,
                              hipStream_t stream) {
  const float* x  = (const float*)d_in[0];
  const float* rw = (const float*)d_in[1];
  const float* rb = (const float*)d_in[2];
  const float* W1 = (const float*)d_in[3];
  const float* b1 = (const float*)d_in[4];
  const float* W2 = (const float*)d_in[5];
  const float* b2 = (const float*)d_in[6];
  float* out = (float*)d_out;

  char* ws = (char*)d_ws;
  int*    counts   = (int*)ws;                        // 32 B
  int*    btok     = (int*)(ws + 256);                // 256 KB
  float*  bw       = (float*)(ws + 256 + 262144);     // 256 KB
  int*    tokrec   = (int*)(ws + 256 + 524288);       // 64 KB
  int*    gcnt     = (int*)(ws + 655360);             // 32 KB  [8][1024]
  int*    base_blk = (int*)(ws + 688128);             // 32 KB  [8][1024]
  int2*   te_l     = (int2*)(ws + 720896);            // 64 KB
  float2* tw       = (float2*)(ws + 786432);          // 64 KB  (ends < 1 MB)
  u16* xb  = (u16*)(ws + (1u << 20));                 // 16 MB
  u16* w1t = xb  + (size_t)NTOK * DIM_;               // 64 MB
  u16* w2t = w1t + (size_t)E_ * H2_ * DIM_;           // 32 MB
  u16* hb  = w2t + (size_t)E_ * DIM_ * HID_;          // ~67 MB
  u16* ybuf = w1t;  // alias: w1t dead after gemm1

  tconv<<<dim3(H2_ / 64, DIM_ / 64, E_), 256, 0, stream>>>(W1, w1t, DIM_, H2_);
  tconv<<<dim3(DIM_ / 64, HID_ / 64, E_), 256, 0, stream>>>(W2, w2t, HID_, DIM_);
  routerA<<<1024, 256, 0, stream>>>(x, rw, rb, xb, gcnt, te_l, tw);
  routerB<<<1, 256, 0, stream>>>(gcnt, base_blk, counts);
  routerC<<<32, 256, 0, stream>>>(te_l, tw, base_blk, btok, bw, tokrec);

  gemm1<<<dim3(H2_ / 128, NTOK / 128, E_), 256, 0, stream>>>(xb, w1t, b1, counts, btok, hb);
  gemm2<<<dim3(DIM_ / 128, NTOK / 128, E_), 256, 0, stream>>>(hb, w2t, b2, counts, bw, ybuf);
  combine<<<NTOK, 256, 0, stream>>>(ybuf, tokrec, counts, out);
}

// Round 12
// 375.901 us; speedup vs baseline: 1.2089x; 1.0137x over previous
//
#include <hip/hip_runtime.h>
#include <stdint.h>

typedef unsigned short u16;

#define E_    8
#define DIM_  1024
#define HID_  2048
#define H2_   4096     // 2*HID
#define NTOK  8192     // B*T
#define SLAB  ((size_t)NTOK * 2 * DIM_)   // u16 elems per ybuf slab (16384*1024)

typedef __attribute__((ext_vector_type(8))) short bf16x8;
typedef __attribute__((ext_vector_type(4))) float f32x4;

__device__ __forceinline__ u16 f2bf(float f) {
  uint32_t u = __builtin_bit_cast(uint32_t, f);
  uint32_t r = (u + 0x7FFFu + ((u >> 16) & 1u)) >> 16;
  return (u16)r;
}
__device__ __forceinline__ float bf2f(u16 u) {
  return __builtin_bit_cast(float, (uint32_t)u << 16);
}

__device__ __forceinline__ void gload16(const void* g, void* l) {
  __builtin_amdgcn_global_load_lds(
      (const __attribute__((address_space(1))) void*)g,
      (__attribute__((address_space(3))) void*)l, 16, 0, 0);
}

// ---------------- fused weight transpose (64x64 tiles) ----------------
// b < 8192 : W1 [e][1024][4096] -> w1t [e][4096][1024]
// else     : W2 [e][2048][1024] -> w2t [e][1024][2048]

__global__ void tconvF(const float* __restrict__ W1, u16* __restrict__ w1t,
                       const float* __restrict__ W2, u16* __restrict__ w2t) {
  __shared__ float t[64][65];
  int b = blockIdx.x;
  const float* src; u16* dst; int R, C, e, bx, by;
  if (b < 8192) {
    e = b >> 10; int rem = b & 1023;
    bx = rem & 63; by = rem >> 6;      // x: C/64=64, y: R/64=16
    src = W1; dst = w1t; R = DIM_; C = H2_;
  } else {
    int b2 = b - 8192;
    e = b2 >> 9; int rem = b2 & 511;
    bx = rem & 15; by = rem >> 4;      // x: C/64=16, y: R/64=32
    src = W2; dst = w2t; R = HID_; C = DIM_;
  }
  int r0 = by * 64, c0 = bx * 64;
  const float* s = src + (size_t)e * R * C;
  u16* d = dst + (size_t)e * R * C;
  int tid = threadIdx.x;
  int rr = tid >> 4, cc = (tid & 15) * 4;
#pragma unroll
  for (int p = 0; p < 4; ++p) {
    float4 v = *(const float4*)(s + (size_t)(r0 + p * 16 + rr) * C + c0 + cc);
    t[p * 16 + rr][cc + 0] = v.x; t[p * 16 + rr][cc + 1] = v.y;
    t[p * 16 + rr][cc + 2] = v.z; t[p * 16 + rr][cc + 3] = v.w;
  }
  __syncthreads();
  int cr = tid >> 3, rc = (tid & 7) * 8;
#pragma unroll
  for (int p = 0; p < 2; ++p) {
    union { u16 u[8]; uint4 v; } w;
#pragma unroll
    for (int j = 0; j < 8; ++j) w.u[j] = f2bf(t[rc + j][p * 32 + cr]);
    *(uint4*)(d + (size_t)(c0 + p * 32 + cr) * R + r0 + rc) = w.v;
  }
}

// ---------------- routerA: logits + top2 + x->bf16, per-block counts ----------------

__global__ void routerA(const float* __restrict__ x, const float* __restrict__ rw,
                        const float* __restrict__ rb, u16* __restrict__ xb,
                        int* __restrict__ gcnt, int2* __restrict__ te_l,
                        float2* __restrict__ tw) {
  __shared__ float srw[E_ * DIM_];
  __shared__ float sb[E_];
  __shared__ int   hcnt[E_];

  int tid = threadIdx.x;
  for (int i = tid; i < E_ * DIM_ / 4; i += 256)
    ((float4*)srw)[i] = ((const float4*)rw)[i];
  if (tid < E_) { sb[tid] = rb[tid]; hcnt[tid] = 0; }
  __syncthreads();

  int wid = tid >> 6, lane = tid & 63;
#pragma unroll
  for (int s = 0; s < 2; ++s) {
    int t = blockIdx.x * 8 + wid * 2 + s;
    const float* xt = x + (size_t)t * DIM_;
    float acc[8] = {0.f, 0.f, 0.f, 0.f, 0.f, 0.f, 0.f, 0.f};
#pragma unroll
    for (int it = 0; it < 4; ++it) {
      int d = it * 256 + lane * 4;
      float4 xv = *(const float4*)(xt + d);
      ushort4 xo;
      xo.x = f2bf(xv.x); xo.y = f2bf(xv.y); xo.z = f2bf(xv.z); xo.w = f2bf(xv.w);
      *(ushort4*)(xb + (size_t)t * DIM_ + d) = xo;
#pragma unroll
      for (int e = 0; e < 8; ++e) {
        float4 rv = *(const float4*)(&srw[e * DIM_ + d]);
        acc[e] += xv.x * rv.x + xv.y * rv.y + xv.z * rv.z + xv.w * rv.w;
      }
    }
#pragma unroll
    for (int e = 0; e < 8; ++e)
#pragma unroll
      for (int off = 32; off; off >>= 1)
        acc[e] += __shfl_xor(acc[e], off, 64);
    if (lane == 0) {
      float v[8];
#pragma unroll
      for (int e = 0; e < 8; ++e) v[e] = acc[e] + sb[e];
      int i0 = 0;
#pragma unroll
      for (int e = 1; e < 8; ++e) if (v[e] > v[i0]) i0 = e;
      int i1 = (i0 == 0) ? 1 : 0;
#pragma unroll
      for (int e = 0; e < 8; ++e) if (e != i0 && v[e] > v[i1]) i1 = e;
      float w0 = 1.f / (1.f + expf(v[i1] - v[i0]));
      int l0 = atomicAdd(&hcnt[i0], 1);
      int l1 = atomicAdd(&hcnt[i1], 1);
      te_l[t] = make_int2((i0 << 8) | l0, (i1 << 8) | l1);
      tw[t] = make_float2(w0, 1.f - w0);
    }
  }
  __syncthreads();
  if (tid < E_) gcnt[tid * 1024 + blockIdx.x] = hcnt[tid];
}

// ---------------- routerB: per-expert exclusive prefix over 1024 blocks ----------------

__global__ void routerB(const int* __restrict__ gcnt, int* __restrict__ base_blk,
                        int* __restrict__ counts) {
  __shared__ int part[256];
  int tid = threadIdx.x;
#pragma unroll
  for (int e = 0; e < 8; ++e) {
    int4 v = *(const int4*)(gcnt + e * 1024 + tid * 4);
    int s = v.x + v.y + v.z + v.w;
    part[tid] = s;
    __syncthreads();
    for (int off = 1; off < 256; off <<= 1) {
      int o = (tid >= off) ? part[tid - off] : 0;
      __syncthreads();
      part[tid] += o;
      __syncthreads();
    }
    int ex = part[tid] - s;
    int tot = part[255];
    int4 b;
    b.x = ex; b.y = ex + v.x; b.z = ex + v.x + v.y; b.w = ex + v.x + v.y + v.z;
    *(int4*)(base_blk + e * 1024 + tid * 4) = b;
    if (tid == 0) counts[e] = tot;
    __syncthreads();
  }
}

// ---------------- routerC: scatter bucket entries ----------------

__global__ void routerC(const int2* __restrict__ te_l, const float2* __restrict__ tw,
                        const int* __restrict__ base_blk, int* __restrict__ btok,
                        float* __restrict__ bw, int* __restrict__ tokrec) {
  int t = blockIdx.x * 256 + threadIdx.x;
  int2 r = te_l[t];
  float2 w = tw[t];
  int b = t >> 3;
  int e0 = r.x >> 8, l0 = r.x & 255;
  int e1 = r.y >> 8, l1 = r.y & 255;
  int p0 = base_blk[e0 * 1024 + b] + l0;
  int p1 = base_blk[e1 * 1024 + b] + l1;
  btok[e0 * NTOK + p0] = t; bw[e0 * NTOK + p0] = w.x; tokrec[t * 2 + 0] = (e0 << 13) | p0;
  btok[e1 * NTOK + p1] = t; bw[e1 * NTOK + p1] = w.y; tokrec[t * 2 + 1] = (e1 << 13) | p1;
}

// ---------------- GEMM1: gathered x @ W1 -> swiglu -> hb (proven) ----------------

__launch_bounds__(256, 4)
__global__ void gemm1(const u16* __restrict__ xb, const u16* __restrict__ w1t,
                      const float* __restrict__ b1, const int* __restrict__ counts,
                      const int* __restrict__ btok, u16* __restrict__ hb) {
  int e = blockIdx.z, mblk = blockIdx.y, nblk = blockIdx.x;
  int cnt = counts[e];
  if (mblk * 128 >= cnt) return;
  int base = 0;
#pragma unroll
  for (int i = 0; i < 8; ++i) base += (i < e) ? counts[i] : 0;

  __shared__ u16 lA[128 * 64];
  __shared__ u16 lB[128 * 64];
  __shared__ int sTok[128];

  int tid = threadIdx.x, wid = tid >> 6, lane = tid & 63;
  if (tid < 128) {
    int gr = mblk * 128 + tid;
    sTok[tid] = (gr < cnt) ? btok[e * NTOK + gr] : btok[e * NTOK];
  }
  __syncthreads();

  f32x4 acc[4][4] = {};
  int wr = wid >> 1, wc = wid & 1;
  int l15 = lane & 15, lhi = lane >> 4;
  const size_t w1e = (size_t)e * H2_ * DIM_;

  int segsw = ((lane & 7) ^ ((lane >> 3) & 7)) * 8;
  const u16* gA[4];
  const u16* gB[4];
#pragma unroll
  for (int i = 0; i < 4; ++i) {
    int r = wid * 32 + i * 8 + (lane >> 3);
    gA[i] = xb + (size_t)sTok[r] * DIM_ + segsw;
    int gcol = nblk * 64 + (r >> 6) * 32 + (r & 31) + ((r >> 5) & 1) * 2048;
    gB[i] = w1t + w1e + (size_t)gcol * DIM_ + segsw;
  }
  int rxor = (l15 & 7) * 8;

  for (int kt = 0; kt < DIM_ / 64; ++kt) {
#pragma unroll
    for (int i = 0; i < 4; ++i)
      gload16(gA[i] + kt * 64, &lA[(wid * 32 + i * 8) * 64]);
#pragma unroll
    for (int i = 0; i < 4; ++i)
      gload16(gB[i] + kt * 64, &lB[(wid * 32 + i * 8) * 64]);
    __syncthreads();
#pragma unroll
    for (int ks = 0; ks < 2; ++ks) {
      int segrd = ((ks * 4 + lhi) * 8) ^ rxor;
      bf16x8 a[4], b[4];
#pragma unroll
      for (int m = 0; m < 4; ++m)
        a[m] = *(const bf16x8*)&lA[(wr * 64 + m * 16 + l15) * 64 + segrd];
#pragma unroll
      for (int n = 0; n < 4; ++n)
        b[n] = *(const bf16x8*)&lB[(wc * 64 + n * 16 + l15) * 64 + segrd];
#pragma unroll
      for (int m = 0; m < 4; ++m)
#pragma unroll
        for (int n = 0; n < 4; ++n)
          acc[m][n] = __builtin_amdgcn_mfma_f32_16x16x32_bf16(a[m], b[n], acc[m][n], 0, 0, 0);
    }
    __syncthreads();
  }

#pragma unroll
  for (int n = 0; n < 2; ++n) {
    int outcol = nblk * 64 + wc * 32 + n * 16 + l15;
    float bb1 = b1[e * H2_ + outcol];
    float bb2 = b1[e * H2_ + outcol + HID_];
#pragma unroll
    for (int m = 0; m < 4; ++m) {
#pragma unroll
      for (int j = 0; j < 4; ++j) {
        int rt = wr * 64 + m * 16 + lhi * 4 + j;
        int gr = mblk * 128 + rt;
        if (gr < cnt) {
          float h1 = acc[m][n][j] + bb1;
          float h2 = acc[m][n + 2][j] + bb2;
          float s = (h1 / (1.f + __expf(-h1))) * h2;
          hb[(size_t)(base + gr) * HID_ + outcol] = f2bf(s);
        }
      }
    }
  }
}

// ---------------- GEMM2 split-K=2: hb @ W2 -> partials to ybuf slabs ----------------
// blockIdx.x: nblk = bx & 7, khalf = bx >> 3. K-range [khalf*1024, +1024).
// slab khalf gets w*(acc + (khalf==0 ? b2 : 0)) in bf16.

__launch_bounds__(256, 4)
__global__ void gemm2(const u16* __restrict__ hb, const u16* __restrict__ w2t,
                      const float* __restrict__ b2, const int* __restrict__ counts,
                      const float* __restrict__ bw, u16* __restrict__ ybuf) {
  int e = blockIdx.z, mblk = blockIdx.y;
  int nblk = blockIdx.x & 7, khalf = blockIdx.x >> 3;
  int cnt = counts[e];
  if (mblk * 128 >= cnt) return;
  int base = 0;
#pragma unroll
  for (int i = 0; i < 8; ++i) base += (i < e) ? counts[i] : 0;

  __shared__ u16 lA[128 * 64];
  __shared__ u16 lB[128 * 64];
  __shared__ float sW[128];

  int tid = threadIdx.x, wid = tid >> 6, lane = tid & 63;
  if (tid < 128) {
    int gr = mblk * 128 + tid;
    sW[tid] = (gr < cnt) ? bw[e * NTOK + gr] : 0.f;
  }
  __syncthreads();

  f32x4 acc[4][4] = {};
  int wr = wid >> 1, wc = wid & 1;
  int l15 = lane & 15, lhi = lane >> 4;

  int segsw = ((lane & 7) ^ ((lane >> 3) & 7)) * 8;
  int koff = khalf * (HID_ / 2);   // u16 offset into K dim
  const u16* gA[4];
  const u16* gB[4];
#pragma unroll
  for (int i = 0; i < 4; ++i) {
    int r = wid * 32 + i * 8 + (lane >> 3);
    gA[i] = hb + (size_t)(base + mblk * 128 + r) * HID_ + koff + segsw;
    gB[i] = w2t + (size_t)e * DIM_ * HID_ + (size_t)(nblk * 128 + r) * HID_ + koff + segsw;
  }
  int rxor = (l15 & 7) * 8;

  for (int kt = 0; kt < HID_ / 128; ++kt) {   // 16 K-steps (half of 32)
#pragma unroll
    for (int i = 0; i < 4; ++i) {
      gload16(gA[i] + kt * 64, &lA[(wid * 32 + i * 8) * 64]);
      gload16(gB[i] + kt * 64, &lB[(wid * 32 + i * 8) * 64]);
    }
    __syncthreads();
#pragma unroll
    for (int ks = 0; ks < 2; ++ks) {
      int segrd = ((ks * 4 + lhi) * 8) ^ rxor;
      bf16x8 a[4], b[4];
#pragma unroll
      for (int m = 0; m < 4; ++m)
        a[m] = *(const bf16x8*)&lA[(wr * 64 + m * 16 + l15) * 64 + segrd];
#pragma unroll
      for (int n = 0; n < 4; ++n)
        b[n] = *(const bf16x8*)&lB[(wc * 64 + n * 16 + l15) * 64 + segrd];
#pragma unroll
      for (int m = 0; m < 4; ++m)
#pragma unroll
        for (int n = 0; n < 4; ++n)
          acc[m][n] = __builtin_amdgcn_mfma_f32_16x16x32_bf16(a[m], b[n], acc[m][n], 0, 0, 0);
    }
    __syncthreads();
  }

  u16* yb = ybuf + (size_t)khalf * SLAB;
#pragma unroll
  for (int n = 0; n < 4; ++n) {
    int col = nblk * 128 + wc * 64 + n * 16 + l15;
    float bb = (khalf == 0) ? b2[e * DIM_ + col] : 0.f;
#pragma unroll
    for (int m = 0; m < 4; ++m) {
#pragma unroll
      for (int j = 0; j < 4; ++j) {
        int rt = wr * 64 + m * 16 + lhi * 4 + j;
        int gr = mblk * 128 + rt;
        if (gr < cnt)
          yb[(size_t)(base + gr) * DIM_ + col] = f2bf(sW[rt] * (acc[m][n][j] + bb));
      }
    }
  }
}

// ---------------- combine: out[t] = sum of 4 slices ----------------
// 2048 blocks x 256 thr; wave w handles token blk*4+w (64 lanes x 16 f32).

__global__ void combine(const u16* __restrict__ ybuf, const int* __restrict__ tokrec,
                        const int* __restrict__ counts, float* __restrict__ out) {
  __shared__ int sbase[8];
  int tid = threadIdx.x;
  if (tid < 8) {
    int b = 0;
#pragma unroll
    for (int e = 0; e < 8; ++e) { if (e == tid) sbase[e] = b; b += counts[e]; }
  }
  __syncthreads();
  int wid = tid >> 6, lane = tid & 63;
  int t = blockIdx.x * 4 + wid;
  int r0 = tokrec[t * 2 + 0], r1 = tokrec[t * 2 + 1];
  size_t s0 = (size_t)(sbase[r0 >> 13] + (r0 & 8191)) * DIM_;
  size_t s1 = (size_t)(sbase[r1 >> 13] + (r1 & 8191)) * DIM_;
#pragma unroll
  for (int p = 0; p < 4; ++p) {
    int c = (lane + p * 64) * 4;
    ushort4 a0 = *(const ushort4*)(ybuf + s0 + c);
    ushort4 a1 = *(const ushort4*)(ybuf + SLAB + s0 + c);
    ushort4 b0 = *(const ushort4*)(ybuf + s1 + c);
    ushort4 b1 = *(const ushort4*)(ybuf + SLAB + s1 + c);
    float4 o;
    o.x = bf2f(a0.x) + bf2f(a1.x) + bf2f(b0.x) + bf2f(b1.x);
    o.y = bf2f(a0.y) + bf2f(a1.y) + bf2f(b0.y) + bf2f(b1.y);
    o.z = bf2f(a0.z) + bf2f(a1.z) + bf2f(b0.z) + bf2f(b1.z);
    o.w = bf2f(a0.w) + bf2f(a1.w) + bf2f(b0.w) + bf2f(b1.w);
    *(float4*)(out + (size_t)t * DIM_ + c) = o;
  }
}

// ---------------- launch ----------------

extern "C" void kernel_launch(void* const* d_in, const int* in_sizes, int n_in,
                              void* d_out, int out_size, void* d_ws, size_t ws_size,
                              hipStream_t stream) {
  const float* x  = (const float*)d_in[0];
  const float* rw = (const float*)d_in[1];
  const float* rb = (const float*)d_in[2];
  const float* W1 = (const float*)d_in[3];
  const float* b1 = (const float*)d_in[4];
  const float* W2 = (const float*)d_in[5];
  const float* b2 = (const float*)d_in[6];
  float* out = (float*)d_out;

  char* ws = (char*)d_ws;
  int*    counts   = (int*)ws;                        // 32 B
  int*    btok     = (int*)(ws + 256);                // 256 KB
  float*  bw       = (float*)(ws + 256 + 262144);     // 256 KB
  int*    tokrec   = (int*)(ws + 256 + 524288);       // 64 KB
  int*    gcnt     = (int*)(ws + 655360);             // 32 KB
  int*    base_blk = (int*)(ws + 688128);             // 32 KB
  int2*   te_l     = (int2*)(ws + 720896);            // 64 KB
  float2* tw       = (float2*)(ws + 786432);          // 64 KB
  u16* xb  = (u16*)(ws + (1u << 20));                 // 16 MB
  u16* w1t = xb  + (size_t)NTOK * DIM_;               // 64 MB
  u16* w2t = w1t + (size_t)E_ * H2_ * DIM_;           // 32 MB
  u16* hb  = w2t + (size_t)E_ * DIM_ * HID_;          // 64 MB (16384 rows used)
  u16* ybuf = w1t;  // 2 slabs x 32 MB = exactly w1t's 64 MB (dead after gemm1)

  tconvF<<<12288, 256, 0, stream>>>(W1, w1t, W2, w2t);
  routerA<<<1024, 256, 0, stream>>>(x, rw, rb, xb, gcnt, te_l, tw);
  routerB<<<1, 256, 0, stream>>>(gcnt, base_blk, counts);
  routerC<<<32, 256, 0, stream>>>(te_l, tw, base_blk, btok, bw, tokrec);

  gemm1<<<dim3(H2_ / 128, NTOK / 128, E_), 256, 0, stream>>>(xb, w1t, b1, counts, btok, hb);
  gemm2<<<dim3(16, NTOK / 128, E_), 256, 0, stream>>>(hb, w2t, b2, counts, bw, ybuf);
  combine<<<NTOK / 4, 256, 0, stream>>>(ybuf, tokrec, counts, out);
}

// Round 13
// 363.442 us; speedup vs baseline: 1.2503x; 1.0343x over previous
//
#include <hip/hip_runtime.h>
#include <stdint.h>

typedef unsigned short u16;

#define E_    8
#define DIM_  1024
#define HID_  2048
#define H2_   4096     // 2*HID
#define NTOK  8192     // B*T
#define SLAB  ((size_t)NTOK * 2 * DIM_)   // u16 elems per ybuf slab

typedef __attribute__((ext_vector_type(8))) short bf16x8;
typedef __attribute__((ext_vector_type(4))) float f32x4;

__device__ __forceinline__ u16 f2bf(float f) {
  uint32_t u = __builtin_bit_cast(uint32_t, f);
  uint32_t r = (u + 0x7FFFu + ((u >> 16) & 1u)) >> 16;
  return (u16)r;
}
__device__ __forceinline__ float bf2f(u16 u) {
  return __builtin_bit_cast(float, (uint32_t)u << 16);
}

__device__ __forceinline__ void gload16(const void* g, void* l) {
  __builtin_amdgcn_global_load_lds(
      (const __attribute__((address_space(1))) void*)g,
      (__attribute__((address_space(3))) void*)l, 16, 0, 0);
}

// ---------------- prep: fused weight transpose + router pass A ----------------
// blocks [0,12288): tconv 64x64 tiles (W1: 8192 blocks, W2: 4096 blocks)
// blocks [12288,13312): routerA (logits + top2 + x->bf16, per-block counts)

__global__ void prep(const float* __restrict__ W1, u16* __restrict__ w1t,
                     const float* __restrict__ W2, u16* __restrict__ w2t,
                     const float* __restrict__ x, const float* __restrict__ rw,
                     const float* __restrict__ rb, u16* __restrict__ xb,
                     int* __restrict__ gcnt, int2* __restrict__ te_l,
                     float2* __restrict__ tw) {
  __shared__ float smem[E_ * DIM_ + 16];   // 33 KB (router view); tconv uses 16.6 KB
  int b = blockIdx.x;
  int tid = threadIdx.x;

  if (b < 12288) {
    // ---- weight transpose ----
    float (*t)[65] = (float(*)[65])smem;
    const float* src; u16* dst; int R, C, e, bx, by;
    if (b < 8192) {
      e = b >> 10; int rem = b & 1023;
      bx = rem & 63; by = rem >> 6;
      src = W1; dst = w1t; R = DIM_; C = H2_;
    } else {
      int b2 = b - 8192;
      e = b2 >> 9; int rem = b2 & 511;
      bx = rem & 15; by = rem >> 4;
      src = W2; dst = w2t; R = HID_; C = DIM_;
    }
    int r0 = by * 64, c0 = bx * 64;
    const float* s = src + (size_t)e * R * C;
    u16* d = dst + (size_t)e * R * C;
    int rr = tid >> 4, cc = (tid & 15) * 4;
#pragma unroll
    for (int p = 0; p < 4; ++p) {
      float4 v = *(const float4*)(s + (size_t)(r0 + p * 16 + rr) * C + c0 + cc);
      t[p * 16 + rr][cc + 0] = v.x; t[p * 16 + rr][cc + 1] = v.y;
      t[p * 16 + rr][cc + 2] = v.z; t[p * 16 + rr][cc + 3] = v.w;
    }
    __syncthreads();
    int cr = tid >> 3, rc = (tid & 7) * 8;
#pragma unroll
    for (int p = 0; p < 2; ++p) {
      union { u16 u[8]; uint4 v; } w;
#pragma unroll
      for (int j = 0; j < 8; ++j) w.u[j] = f2bf(t[rc + j][p * 32 + cr]);
      *(uint4*)(d + (size_t)(c0 + p * 32 + cr) * R + r0 + rc) = w.v;
    }
  } else {
    // ---- routerA ----
    int rblk = b - 12288;              // 0..1023
    float* srw = smem;
    float* sb  = smem + E_ * DIM_;
    int*   hcnt = (int*)(smem + E_ * DIM_ + 8);

    for (int i = tid; i < E_ * DIM_ / 4; i += 256)
      ((float4*)srw)[i] = ((const float4*)rw)[i];
    if (tid < E_) { sb[tid] = rb[tid]; hcnt[tid] = 0; }
    __syncthreads();

    int wid = tid >> 6, lane = tid & 63;
#pragma unroll
    for (int s = 0; s < 2; ++s) {
      int t = rblk * 8 + wid * 2 + s;
      const float* xt = x + (size_t)t * DIM_;
      float acc[8] = {0.f, 0.f, 0.f, 0.f, 0.f, 0.f, 0.f, 0.f};
#pragma unroll
      for (int it = 0; it < 4; ++it) {
        int d = it * 256 + lane * 4;
        float4 xv = *(const float4*)(xt + d);
        ushort4 xo;
        xo.x = f2bf(xv.x); xo.y = f2bf(xv.y); xo.z = f2bf(xv.z); xo.w = f2bf(xv.w);
        *(ushort4*)(xb + (size_t)t * DIM_ + d) = xo;
#pragma unroll
        for (int e = 0; e < 8; ++e) {
          float4 rv = *(const float4*)(&srw[e * DIM_ + d]);
          acc[e] += xv.x * rv.x + xv.y * rv.y + xv.z * rv.z + xv.w * rv.w;
        }
      }
#pragma unroll
      for (int e = 0; e < 8; ++e)
#pragma unroll
        for (int off = 32; off; off >>= 1)
          acc[e] += __shfl_xor(acc[e], off, 64);
      if (lane == 0) {
        float v[8];
#pragma unroll
        for (int e = 0; e < 8; ++e) v[e] = acc[e] + sb[e];
        int i0 = 0;
#pragma unroll
        for (int e = 1; e < 8; ++e) if (v[e] > v[i0]) i0 = e;
        int i1 = (i0 == 0) ? 1 : 0;
#pragma unroll
        for (int e = 0; e < 8; ++e) if (e != i0 && v[e] > v[i1]) i1 = e;
        float w0 = 1.f / (1.f + expf(v[i1] - v[i0]));
        int l0 = atomicAdd(&hcnt[i0], 1);
        int l1 = atomicAdd(&hcnt[i1], 1);
        te_l[t] = make_int2((i0 << 8) | l0, (i1 << 8) | l1);
        tw[t] = make_float2(w0, 1.f - w0);
      }
    }
    __syncthreads();
    if (tid < E_) gcnt[tid * 1024 + rblk] = hcnt[tid];
  }
}

// ---------------- routerBC: redundant 8-expert batched scan + scatter ----------------
// 32 blocks; each scans gcnt for all experts (one batched pass) and scatters
// its 256 tokens. Block 0 writes counts.

__global__ void routerBC(const int* __restrict__ gcnt, int* __restrict__ counts,
                         const int2* __restrict__ te_l, const float2* __restrict__ tw,
                         int* __restrict__ btok, float* __restrict__ bw,
                         int* __restrict__ tokrec) {
  __shared__ int part[8][256];
  __shared__ int sbb[8][32];
  int tid = threadIdx.x, b = blockIdx.x;

  int4 v[8]; int s[8];
#pragma unroll
  for (int e = 0; e < 8; ++e) {
    v[e] = *(const int4*)(gcnt + e * 1024 + tid * 4);
    s[e] = v[e].x + v[e].y + v[e].z + v[e].w;
    part[e][tid] = s[e];
  }
  __syncthreads();
  for (int off = 1; off < 256; off <<= 1) {
    int o[8];
#pragma unroll
    for (int e = 0; e < 8; ++e) o[e] = (tid >= off) ? part[e][tid - off] : 0;
    __syncthreads();
#pragma unroll
    for (int e = 0; e < 8; ++e) part[e][tid] += o[e];
    __syncthreads();
  }
  if ((tid >> 3) == b) {               // this thread's 4 columns lie in our 32
    int lc = (tid & 7) * 4;
#pragma unroll
    for (int e = 0; e < 8; ++e) {
      int ex = part[e][tid] - s[e];
      sbb[e][lc + 0] = ex;
      sbb[e][lc + 1] = ex + v[e].x;
      sbb[e][lc + 2] = ex + v[e].x + v[e].y;
      sbb[e][lc + 3] = ex + v[e].x + v[e].y + v[e].z;
    }
  }
  if (b == 0 && tid < 8) counts[tid] = part[tid][255];
  __syncthreads();

  int t = b * 256 + tid;
  int2 r = te_l[t];
  float2 w = tw[t];
  int blk_l = tid >> 3;                // (t>>3) - b*32
  int e0 = r.x >> 8, l0 = r.x & 255;
  int e1 = r.y >> 8, l1 = r.y & 255;
  int p0 = sbb[e0][blk_l] + l0;
  int p1 = sbb[e1][blk_l] + l1;
  btok[e0 * NTOK + p0] = t; bw[e0 * NTOK + p0] = w.x; tokrec[t * 2 + 0] = (e0 << 13) | p0;
  btok[e1 * NTOK + p1] = t; bw[e1 * NTOK + p1] = w.y; tokrec[t * 2 + 1] = (e1 << 13) | p1;
}

// ---------------- GEMM1: gathered x @ W1 -> swiglu -> hb (proven) ----------------

__launch_bounds__(256, 4)
__global__ void gemm1(const u16* __restrict__ xb, const u16* __restrict__ w1t,
                      const float* __restrict__ b1, const int* __restrict__ counts,
                      const int* __restrict__ btok, u16* __restrict__ hb) {
  int e = blockIdx.z, mblk = blockIdx.y, nblk = blockIdx.x;
  int cnt = counts[e];
  if (mblk * 128 >= cnt) return;
  int base = 0;
#pragma unroll
  for (int i = 0; i < 8; ++i) base += (i < e) ? counts[i] : 0;

  __shared__ u16 lA[128 * 64];
  __shared__ u16 lB[128 * 64];
  __shared__ int sTok[128];

  int tid = threadIdx.x, wid = tid >> 6, lane = tid & 63;
  if (tid < 128) {
    int gr = mblk * 128 + tid;
    sTok[tid] = (gr < cnt) ? btok[e * NTOK + gr] : btok[e * NTOK];
  }
  __syncthreads();

  f32x4 acc[4][4] = {};
  int wr = wid >> 1, wc = wid & 1;
  int l15 = lane & 15, lhi = lane >> 4;
  const size_t w1e = (size_t)e * H2_ * DIM_;

  int segsw = ((lane & 7) ^ ((lane >> 3) & 7)) * 8;
  const u16* gA[4];
  const u16* gB[4];
#pragma unroll
  for (int i = 0; i < 4; ++i) {
    int r = wid * 32 + i * 8 + (lane >> 3);
    gA[i] = xb + (size_t)sTok[r] * DIM_ + segsw;
    int gcol = nblk * 64 + (r >> 6) * 32 + (r & 31) + ((r >> 5) & 1) * 2048;
    gB[i] = w1t + w1e + (size_t)gcol * DIM_ + segsw;
  }
  int rxor = (l15 & 7) * 8;

  for (int kt = 0; kt < DIM_ / 64; ++kt) {
#pragma unroll
    for (int i = 0; i < 4; ++i)
      gload16(gA[i] + kt * 64, &lA[(wid * 32 + i * 8) * 64]);
#pragma unroll
    for (int i = 0; i < 4; ++i)
      gload16(gB[i] + kt * 64, &lB[(wid * 32 + i * 8) * 64]);
    __syncthreads();
#pragma unroll
    for (int ks = 0; ks < 2; ++ks) {
      int segrd = ((ks * 4 + lhi) * 8) ^ rxor;
      bf16x8 a[4], b[4];
#pragma unroll
      for (int m = 0; m < 4; ++m)
        a[m] = *(const bf16x8*)&lA[(wr * 64 + m * 16 + l15) * 64 + segrd];
#pragma unroll
      for (int n = 0; n < 4; ++n)
        b[n] = *(const bf16x8*)&lB[(wc * 64 + n * 16 + l15) * 64 + segrd];
#pragma unroll
      for (int m = 0; m < 4; ++m)
#pragma unroll
        for (int n = 0; n < 4; ++n)
          acc[m][n] = __builtin_amdgcn_mfma_f32_16x16x32_bf16(a[m], b[n], acc[m][n], 0, 0, 0);
    }
    __syncthreads();
  }

#pragma unroll
  for (int n = 0; n < 2; ++n) {
    int outcol = nblk * 64 + wc * 32 + n * 16 + l15;
    float bb1 = b1[e * H2_ + outcol];
    float bb2 = b1[e * H2_ + outcol + HID_];
#pragma unroll
    for (int m = 0; m < 4; ++m) {
#pragma unroll
      for (int j = 0; j < 4; ++j) {
        int rt = wr * 64 + m * 16 + lhi * 4 + j;
        int gr = mblk * 128 + rt;
        if (gr < cnt) {
          float h1 = acc[m][n][j] + bb1;
          float h2 = acc[m][n + 2][j] + bb2;
          float s = (h1 / (1.f + __expf(-h1))) * h2;
          hb[(size_t)(base + gr) * HID_ + outcol] = f2bf(s);
        }
      }
    }
  }
}

// ---------------- GEMM2 split-K=2: hb @ W2 -> partials to ybuf slabs ----------------

__launch_bounds__(256, 4)
__global__ void gemm2(const u16* __restrict__ hb, const u16* __restrict__ w2t,
                      const float* __restrict__ b2, const int* __restrict__ counts,
                      const float* __restrict__ bw, u16* __restrict__ ybuf) {
  int e = blockIdx.z, mblk = blockIdx.y;
  int nblk = blockIdx.x & 7, khalf = blockIdx.x >> 3;
  int cnt = counts[e];
  if (mblk * 128 >= cnt) return;
  int base = 0;
#pragma unroll
  for (int i = 0; i < 8; ++i) base += (i < e) ? counts[i] : 0;

  __shared__ u16 lA[128 * 64];
  __shared__ u16 lB[128 * 64];
  __shared__ float sW[128];

  int tid = threadIdx.x, wid = tid >> 6, lane = tid & 63;
  if (tid < 128) {
    int gr = mblk * 128 + tid;
    sW[tid] = (gr < cnt) ? bw[e * NTOK + gr] : 0.f;
  }
  __syncthreads();

  f32x4 acc[4][4] = {};
  int wr = wid >> 1, wc = wid & 1;
  int l15 = lane & 15, lhi = lane >> 4;

  int segsw = ((lane & 7) ^ ((lane >> 3) & 7)) * 8;
  int koff = khalf * (HID_ / 2);
  const u16* gA[4];
  const u16* gB[4];
#pragma unroll
  for (int i = 0; i < 4; ++i) {
    int r = wid * 32 + i * 8 + (lane >> 3);
    gA[i] = hb + (size_t)(base + mblk * 128 + r) * HID_ + koff + segsw;
    gB[i] = w2t + (size_t)e * DIM_ * HID_ + (size_t)(nblk * 128 + r) * HID_ + koff + segsw;
  }
  int rxor = (l15 & 7) * 8;

  for (int kt = 0; kt < HID_ / 128; ++kt) {
#pragma unroll
    for (int i = 0; i < 4; ++i) {
      gload16(gA[i] + kt * 64, &lA[(wid * 32 + i * 8) * 64]);
      gload16(gB[i] + kt * 64, &lB[(wid * 32 + i * 8) * 64]);
    }
    __syncthreads();
#pragma unroll
    for (int ks = 0; ks < 2; ++ks) {
      int segrd = ((ks * 4 + lhi) * 8) ^ rxor;
      bf16x8 a[4], b[4];
#pragma unroll
      for (int m = 0; m < 4; ++m)
        a[m] = *(const bf16x8*)&lA[(wr * 64 + m * 16 + l15) * 64 + segrd];
#pragma unroll
      for (int n = 0; n < 4; ++n)
        b[n] = *(const bf16x8*)&lB[(wc * 64 + n * 16 + l15) * 64 + segrd];
#pragma unroll
      for (int m = 0; m < 4; ++m)
#pragma unroll
        for (int n = 0; n < 4; ++n)
          acc[m][n] = __builtin_amdgcn_mfma_f32_16x16x32_bf16(a[m], b[n], acc[m][n], 0, 0, 0);
    }
    __syncthreads();
  }

  u16* yb = ybuf + (size_t)khalf * SLAB;
#pragma unroll
  for (int n = 0; n < 4; ++n) {
    int col = nblk * 128 + wc * 64 + n * 16 + l15;
    float bb = (khalf == 0) ? b2[e * DIM_ + col] : 0.f;
#pragma unroll
    for (int m = 0; m < 4; ++m) {
#pragma unroll
      for (int j = 0; j < 4; ++j) {
        int rt = wr * 64 + m * 16 + lhi * 4 + j;
        int gr = mblk * 128 + rt;
        if (gr < cnt)
          yb[(size_t)(base + gr) * DIM_ + col] = f2bf(sW[rt] * (acc[m][n][j] + bb));
      }
    }
  }
}

// ---------------- combine: out[t] = sum of 4 slices ----------------

__global__ void combine(const u16* __restrict__ ybuf, const int* __restrict__ tokrec,
                        const int* __restrict__ counts, float* __restrict__ out) {
  __shared__ int sbase[8];
  int tid = threadIdx.x;
  if (tid < 8) {
    int b = 0;
#pragma unroll
    for (int e = 0; e < 8; ++e) { if (e == tid) sbase[e] = b; b += counts[e]; }
  }
  __syncthreads();
  int wid = tid >> 6, lane = tid & 63;
  int t = blockIdx.x * 4 + wid;
  int r0 = tokrec[t * 2 + 0], r1 = tokrec[t * 2 + 1];
  size_t s0 = (size_t)(sbase[r0 >> 13] + (r0 & 8191)) * DIM_;
  size_t s1 = (size_t)(sbase[r1 >> 13] + (r1 & 8191)) * DIM_;
#pragma unroll
  for (int p = 0; p < 4; ++p) {
    int c = (lane + p * 64) * 4;
    ushort4 a0 = *(const ushort4*)(ybuf + s0 + c);
    ushort4 a1 = *(const ushort4*)(ybuf + SLAB + s0 + c);
    ushort4 b0 = *(const ushort4*)(ybuf + s1 + c);
    ushort4 b1 = *(const ushort4*)(ybuf + SLAB + s1 + c);
    float4 o;
    o.x = bf2f(a0.x) + bf2f(a1.x) + bf2f(b0.x) + bf2f(b1.x);
    o.y = bf2f(a0.y) + bf2f(a1.y) + bf2f(b0.y) + bf2f(b1.y);
    o.z = bf2f(a0.z) + bf2f(a1.z) + bf2f(b0.z) + bf2f(b1.z);
    o.w = bf2f(a0.w) + bf2f(a1.w) + bf2f(b0.w) + bf2f(b1.w);
    *(float4*)(out + (size_t)t * DIM_ + c) = o;
  }
}

// ---------------- launch ----------------

extern "C" void kernel_launch(void* const* d_in, const int* in_sizes, int n_in,
                              void* d_out, int out_size, void* d_ws, size_t ws_size,
                              hipStream_t stream) {
  const float* x  = (const float*)d_in[0];
  const float* rw = (const float*)d_in[1];
  const float* rb = (const float*)d_in[2];
  const float* W1 = (const float*)d_in[3];
  const float* b1 = (const float*)d_in[4];
  const float* W2 = (const float*)d_in[5];
  const float* b2 = (const float*)d_in[6];
  float* out = (float*)d_out;

  char* ws = (char*)d_ws;
  int*    counts   = (int*)ws;                        // 32 B
  int*    btok     = (int*)(ws + 256);                // 256 KB
  float*  bw       = (float*)(ws + 256 + 262144);     // 256 KB
  int*    tokrec   = (int*)(ws + 256 + 524288);       // 64 KB
  int*    gcnt     = (int*)(ws + 655360);             // 32 KB
  int2*   te_l     = (int2*)(ws + 720896);            // 64 KB
  float2* tw       = (float2*)(ws + 786432);          // 64 KB
  u16* xb  = (u16*)(ws + (1u << 20));                 // 16 MB
  u16* w1t = xb  + (size_t)NTOK * DIM_;               // 64 MB
  u16* w2t = w1t + (size_t)E_ * H2_ * DIM_;           // 32 MB
  u16* hb  = w2t + (size_t)E_ * DIM_ * HID_;          // 64 MB
  u16* ybuf = w1t;  // 2 slabs x 32 MB aliasing w1t (dead after gemm1)

  prep<<<13312, 256, 0, stream>>>(W1, w1t, W2, w2t, x, rw, rb, xb, gcnt, te_l, tw);
  routerBC<<<32, 256, 0, stream>>>(gcnt, counts, te_l, tw, btok, bw, tokrec);

  gemm1<<<dim3(H2_ / 128, NTOK / 128, E_), 256, 0, stream>>>(xb, w1t, b1, counts, btok, hb);
  gemm2<<<dim3(16, NTOK / 128, E_), 256, 0, stream>>>(hb, w2t, b2, counts, bw, ybuf);
  combine<<<NTOK / 4, 256, 0, stream>>>(ybuf, tokrec, counts, out);
}

// Round 14
// 358.196 us; speedup vs baseline: 1.2686x; 1.0146x over previous
//
#include <hip/hip_runtime.h>
#include <stdint.h>

typedef unsigned short u16;

#define E_    8
#define DIM_  1024
#define HID_  2048
#define H2_   4096     // 2*HID
#define NTOK  8192     // B*T
#define SLAB  ((size_t)NTOK * 2 * DIM_)   // u16 elems per ybuf slab

typedef __attribute__((ext_vector_type(8))) short bf16x8;
typedef __attribute__((ext_vector_type(4))) float f32x4;

__device__ __forceinline__ u16 f2bf(float f) {
  uint32_t u = __builtin_bit_cast(uint32_t, f);
  uint32_t r = (u + 0x7FFFu + ((u >> 16) & 1u)) >> 16;
  return (u16)r;
}
__device__ __forceinline__ float bf2f(u16 u) {
  return __builtin_bit_cast(float, (uint32_t)u << 16);
}

__device__ __forceinline__ void gload16(const void* g, void* l) {
  __builtin_amdgcn_global_load_lds(
      (const __attribute__((address_space(1))) void*)g,
      (__attribute__((address_space(3))) void*)l, 16, 0, 0);
}

// ---------------- prep: fused weight transpose + router pass A ----------------

__global__ void prep(const float* __restrict__ W1, u16* __restrict__ w1t,
                     const float* __restrict__ W2, u16* __restrict__ w2t,
                     const float* __restrict__ x, const float* __restrict__ rw,
                     const float* __restrict__ rb, u16* __restrict__ xb,
                     int* __restrict__ gcnt, int2* __restrict__ te_l,
                     float2* __restrict__ tw) {
  __shared__ float smem[E_ * DIM_ + 16];
  int b = blockIdx.x;
  int tid = threadIdx.x;

  if (b < 12288) {
    float (*t)[65] = (float(*)[65])smem;
    const float* src; u16* dst; int R, C, e, bx, by;
    if (b < 8192) {
      e = b >> 10; int rem = b & 1023;
      bx = rem & 63; by = rem >> 6;
      src = W1; dst = w1t; R = DIM_; C = H2_;
    } else {
      int b2 = b - 8192;
      e = b2 >> 9; int rem = b2 & 511;
      bx = rem & 15; by = rem >> 4;
      src = W2; dst = w2t; R = HID_; C = DIM_;
    }
    int r0 = by * 64, c0 = bx * 64;
    const float* s = src + (size_t)e * R * C;
    u16* d = dst + (size_t)e * R * C;
    int rr = tid >> 4, cc = (tid & 15) * 4;
#pragma unroll
    for (int p = 0; p < 4; ++p) {
      float4 v = *(const float4*)(s + (size_t)(r0 + p * 16 + rr) * C + c0 + cc);
      t[p * 16 + rr][cc + 0] = v.x; t[p * 16 + rr][cc + 1] = v.y;
      t[p * 16 + rr][cc + 2] = v.z; t[p * 16 + rr][cc + 3] = v.w;
    }
    __syncthreads();
    int cr = tid >> 3, rc = (tid & 7) * 8;
#pragma unroll
    for (int p = 0; p < 2; ++p) {
      union { u16 u[8]; uint4 v; } w;
#pragma unroll
      for (int j = 0; j < 8; ++j) w.u[j] = f2bf(t[rc + j][p * 32 + cr]);
      *(uint4*)(d + (size_t)(c0 + p * 32 + cr) * R + r0 + rc) = w.v;
    }
  } else {
    int rblk = b - 12288;
    float* srw = smem;
    float* sb  = smem + E_ * DIM_;
    int*   hcnt = (int*)(smem + E_ * DIM_ + 8);

    for (int i = tid; i < E_ * DIM_ / 4; i += 256)
      ((float4*)srw)[i] = ((const float4*)rw)[i];
    if (tid < E_) { sb[tid] = rb[tid]; hcnt[tid] = 0; }
    __syncthreads();

    int wid = tid >> 6, lane = tid & 63;
#pragma unroll
    for (int s = 0; s < 2; ++s) {
      int t = rblk * 8 + wid * 2 + s;
      const float* xt = x + (size_t)t * DIM_;
      float acc[8] = {0.f, 0.f, 0.f, 0.f, 0.f, 0.f, 0.f, 0.f};
#pragma unroll
      for (int it = 0; it < 4; ++it) {
        int d = it * 256 + lane * 4;
        float4 xv = *(const float4*)(xt + d);
        ushort4 xo;
        xo.x = f2bf(xv.x); xo.y = f2bf(xv.y); xo.z = f2bf(xv.z); xo.w = f2bf(xv.w);
        *(ushort4*)(xb + (size_t)t * DIM_ + d) = xo;
#pragma unroll
        for (int e = 0; e < 8; ++e) {
          float4 rv = *(const float4*)(&srw[e * DIM_ + d]);
          acc[e] += xv.x * rv.x + xv.y * rv.y + xv.z * rv.z + xv.w * rv.w;
        }
      }
#pragma unroll
      for (int e = 0; e < 8; ++e)
#pragma unroll
        for (int off = 32; off; off >>= 1)
          acc[e] += __shfl_xor(acc[e], off, 64);
      if (lane == 0) {
        float v[8];
#pragma unroll
        for (int e = 0; e < 8; ++e) v[e] = acc[e] + sb[e];
        int i0 = 0;
#pragma unroll
        for (int e = 1; e < 8; ++e) if (v[e] > v[i0]) i0 = e;
        int i1 = (i0 == 0) ? 1 : 0;
#pragma unroll
        for (int e = 0; e < 8; ++e) if (e != i0 && v[e] > v[i1]) i1 = e;
        float w0 = 1.f / (1.f + expf(v[i1] - v[i0]));
        int l0 = atomicAdd(&hcnt[i0], 1);
        int l1 = atomicAdd(&hcnt[i1], 1);
        te_l[t] = make_int2((i0 << 8) | l0, (i1 << 8) | l1);
        tw[t] = make_float2(w0, 1.f - w0);
      }
    }
    __syncthreads();
    if (tid < E_) gcnt[tid * 1024 + rblk] = hcnt[tid];
  }
}

// ---------------- routerBC: redundant 8-expert batched scan + scatter ----------------

__global__ void routerBC(const int* __restrict__ gcnt, int* __restrict__ counts,
                         const int2* __restrict__ te_l, const float2* __restrict__ tw,
                         int* __restrict__ btok, float* __restrict__ bw,
                         int* __restrict__ tokrec) {
  __shared__ int part[8][256];
  __shared__ int sbb[8][32];
  int tid = threadIdx.x, b = blockIdx.x;

  int4 v[8]; int s[8];
#pragma unroll
  for (int e = 0; e < 8; ++e) {
    v[e] = *(const int4*)(gcnt + e * 1024 + tid * 4);
    s[e] = v[e].x + v[e].y + v[e].z + v[e].w;
    part[e][tid] = s[e];
  }
  __syncthreads();
  for (int off = 1; off < 256; off <<= 1) {
    int o[8];
#pragma unroll
    for (int e = 0; e < 8; ++e) o[e] = (tid >= off) ? part[e][tid - off] : 0;
    __syncthreads();
#pragma unroll
    for (int e = 0; e < 8; ++e) part[e][tid] += o[e];
    __syncthreads();
  }
  if ((tid >> 3) == b) {
    int lc = (tid & 7) * 4;
#pragma unroll
    for (int e = 0; e < 8; ++e) {
      int ex = part[e][tid] - s[e];
      sbb[e][lc + 0] = ex;
      sbb[e][lc + 1] = ex + v[e].x;
      sbb[e][lc + 2] = ex + v[e].x + v[e].y;
      sbb[e][lc + 3] = ex + v[e].x + v[e].y + v[e].z;
    }
  }
  if (b == 0 && tid < 8) counts[tid] = part[tid][255];
  __syncthreads();

  int t = b * 256 + tid;
  int2 r = te_l[t];
  float2 w = tw[t];
  int blk_l = tid >> 3;
  int e0 = r.x >> 8, l0 = r.x & 255;
  int e1 = r.y >> 8, l1 = r.y & 255;
  int p0 = sbb[e0][blk_l] + l0;
  int p1 = sbb[e1][blk_l] + l1;
  btok[e0 * NTOK + p0] = t; bw[e0 * NTOK + p0] = w.x; tokrec[t * 2 + 0] = (e0 << 13) | p0;
  btok[e1 * NTOK + p1] = t; bw[e1 * NTOK + p1] = w.y; tokrec[t * 2 + 1] = (e1 << 13) | p1;
}

// ---------------- GEMM1: gathered x @ W1 -> swiglu -> hb ----------------
// 1D grid 16384, XCD-chunked: swz=(bid%8)*2048+bid/8 -> one expert per XCD,
// nblk fastest inside chunk (A-tile reused 32x back-to-back in one L2).

__launch_bounds__(256, 4)
__global__ void gemm1(const u16* __restrict__ xb, const u16* __restrict__ w1t,
                      const float* __restrict__ b1, const int* __restrict__ counts,
                      const int* __restrict__ btok, u16* __restrict__ hb) {
  int bid = blockIdx.x;
  int swz = (bid & 7) * 2048 + (bid >> 3);
  int e = swz >> 11;
  int rem = swz & 2047;
  int mblk = rem >> 5, nblk = rem & 31;

  int cnt = counts[e];
  if (mblk * 128 >= cnt) return;
  int base = 0;
#pragma unroll
  for (int i = 0; i < 8; ++i) base += (i < e) ? counts[i] : 0;

  __shared__ u16 lA[128 * 64];
  __shared__ u16 lB[128 * 64];
  __shared__ int sTok[128];

  int tid = threadIdx.x, wid = tid >> 6, lane = tid & 63;
  if (tid < 128) {
    int gr = mblk * 128 + tid;
    sTok[tid] = (gr < cnt) ? btok[e * NTOK + gr] : btok[e * NTOK];
  }
  __syncthreads();

  f32x4 acc[4][4] = {};
  int wr = wid >> 1, wc = wid & 1;
  int l15 = lane & 15, lhi = lane >> 4;
  const size_t w1e = (size_t)e * H2_ * DIM_;

  int segsw = ((lane & 7) ^ ((lane >> 3) & 7)) * 8;
  const u16* gA[4];
  const u16* gB[4];
#pragma unroll
  for (int i = 0; i < 4; ++i) {
    int r = wid * 32 + i * 8 + (lane >> 3);
    gA[i] = xb + (size_t)sTok[r] * DIM_ + segsw;
    int gcol = nblk * 64 + (r >> 6) * 32 + (r & 31) + ((r >> 5) & 1) * 2048;
    gB[i] = w1t + w1e + (size_t)gcol * DIM_ + segsw;
  }
  int rxor = (l15 & 7) * 8;

  for (int kt = 0; kt < DIM_ / 64; ++kt) {
#pragma unroll
    for (int i = 0; i < 4; ++i)
      gload16(gA[i] + kt * 64, &lA[(wid * 32 + i * 8) * 64]);
#pragma unroll
    for (int i = 0; i < 4; ++i)
      gload16(gB[i] + kt * 64, &lB[(wid * 32 + i * 8) * 64]);
    __syncthreads();
#pragma unroll
    for (int ks = 0; ks < 2; ++ks) {
      int segrd = ((ks * 4 + lhi) * 8) ^ rxor;
      bf16x8 a[4], b[4];
#pragma unroll
      for (int m = 0; m < 4; ++m)
        a[m] = *(const bf16x8*)&lA[(wr * 64 + m * 16 + l15) * 64 + segrd];
#pragma unroll
      for (int n = 0; n < 4; ++n)
        b[n] = *(const bf16x8*)&lB[(wc * 64 + n * 16 + l15) * 64 + segrd];
#pragma unroll
      for (int m = 0; m < 4; ++m)
#pragma unroll
        for (int n = 0; n < 4; ++n)
          acc[m][n] = __builtin_amdgcn_mfma_f32_16x16x32_bf16(a[m], b[n], acc[m][n], 0, 0, 0);
    }
    __syncthreads();
  }

#pragma unroll
  for (int n = 0; n < 2; ++n) {
    int outcol = nblk * 64 + wc * 32 + n * 16 + l15;
    float bb1 = b1[e * H2_ + outcol];
    float bb2 = b1[e * H2_ + outcol + HID_];
#pragma unroll
    for (int m = 0; m < 4; ++m) {
#pragma unroll
      for (int j = 0; j < 4; ++j) {
        int rt = wr * 64 + m * 16 + lhi * 4 + j;
        int gr = mblk * 128 + rt;
        if (gr < cnt) {
          float h1 = acc[m][n][j] + bb1;
          float h2 = acc[m][n + 2][j] + bb2;
          float s = (h1 / (1.f + __expf(-h1))) * h2;
          hb[(size_t)(base + gr) * HID_ + outcol] = f2bf(s);
        }
      }
    }
  }
}

// ---------------- GEMM2 split-K=2, XCD-chunked 1D grid (8192 blocks) ----------------

__launch_bounds__(256, 4)
__global__ void gemm2(const u16* __restrict__ hb, const u16* __restrict__ w2t,
                      const float* __restrict__ b2, const int* __restrict__ counts,
                      const float* __restrict__ bw, u16* __restrict__ ybuf) {
  int bid = blockIdx.x;
  int swz = (bid & 7) * 1024 + (bid >> 3);
  int e = swz >> 10;
  int rem = swz & 1023;
  int mblk = rem >> 4;
  int nblk = rem & 7, khalf = (rem >> 3) & 1;

  int cnt = counts[e];
  if (mblk * 128 >= cnt) return;
  int base = 0;
#pragma unroll
  for (int i = 0; i < 8; ++i) base += (i < e) ? counts[i] : 0;

  __shared__ u16 lA[128 * 64];
  __shared__ u16 lB[128 * 64];
  __shared__ float sW[128];

  int tid = threadIdx.x, wid = tid >> 6, lane = tid & 63;
  if (tid < 128) {
    int gr = mblk * 128 + tid;
    sW[tid] = (gr < cnt) ? bw[e * NTOK + gr] : 0.f;
  }
  __syncthreads();

  f32x4 acc[4][4] = {};
  int wr = wid >> 1, wc = wid & 1;
  int l15 = lane & 15, lhi = lane >> 4;

  int segsw = ((lane & 7) ^ ((lane >> 3) & 7)) * 8;
  int koff = khalf * (HID_ / 2);
  const u16* gA[4];
  const u16* gB[4];
#pragma unroll
  for (int i = 0; i < 4; ++i) {
    int r = wid * 32 + i * 8 + (lane >> 3);
    gA[i] = hb + (size_t)(base + mblk * 128 + r) * HID_ + koff + segsw;
    gB[i] = w2t + (size_t)e * DIM_ * HID_ + (size_t)(nblk * 128 + r) * HID_ + koff + segsw;
  }
  int rxor = (l15 & 7) * 8;

  for (int kt = 0; kt < HID_ / 128; ++kt) {
#pragma unroll
    for (int i = 0; i < 4; ++i) {
      gload16(gA[i] + kt * 64, &lA[(wid * 32 + i * 8) * 64]);
      gload16(gB[i] + kt * 64, &lB[(wid * 32 + i * 8) * 64]);
    }
    __syncthreads();
#pragma unroll
    for (int ks = 0; ks < 2; ++ks) {
      int segrd = ((ks * 4 + lhi) * 8) ^ rxor;
      bf16x8 a[4], b[4];
#pragma unroll
      for (int m = 0; m < 4; ++m)
        a[m] = *(const bf16x8*)&lA[(wr * 64 + m * 16 + l15) * 64 + segrd];
#pragma unroll
      for (int n = 0; n < 4; ++n)
        b[n] = *(const bf16x8*)&lB[(wc * 64 + n * 16 + l15) * 64 + segrd];
#pragma unroll
      for (int m = 0; m < 4; ++m)
#pragma unroll
        for (int n = 0; n < 4; ++n)
          acc[m][n] = __builtin_amdgcn_mfma_f32_16x16x32_bf16(a[m], b[n], acc[m][n], 0, 0, 0);
    }
    __syncthreads();
  }

  u16* yb = ybuf + (size_t)khalf * SLAB;
#pragma unroll
  for (int n = 0; n < 4; ++n) {
    int col = nblk * 128 + wc * 64 + n * 16 + l15;
    float bb = (khalf == 0) ? b2[e * DIM_ + col] : 0.f;
#pragma unroll
    for (int m = 0; m < 4; ++m) {
#pragma unroll
      for (int j = 0; j < 4; ++j) {
        int rt = wr * 64 + m * 16 + lhi * 4 + j;
        int gr = mblk * 128 + rt;
        if (gr < cnt)
          yb[(size_t)(base + gr) * DIM_ + col] = f2bf(sW[rt] * (acc[m][n][j] + bb));
      }
    }
  }
}

// ---------------- combine: out[t] = sum of 4 slices ----------------

__global__ void combine(const u16* __restrict__ ybuf, const int* __restrict__ tokrec,
                        const int* __restrict__ counts, float* __restrict__ out) {
  __shared__ int sbase[8];
  int tid = threadIdx.x;
  if (tid < 8) {
    int b = 0;
#pragma unroll
    for (int e = 0; e < 8; ++e) { if (e == tid) sbase[e] = b; b += counts[e]; }
  }
  __syncthreads();
  int wid = tid >> 6, lane = tid & 63;
  int t = blockIdx.x * 4 + wid;
  int r0 = tokrec[t * 2 + 0], r1 = tokrec[t * 2 + 1];
  size_t s0 = (size_t)(sbase[r0 >> 13] + (r0 & 8191)) * DIM_;
  size_t s1 = (size_t)(sbase[r1 >> 13] + (r1 & 8191)) * DIM_;
#pragma unroll
  for (int p = 0; p < 4; ++p) {
    int c = (lane + p * 64) * 4;
    ushort4 a0 = *(const ushort4*)(ybuf + s0 + c);
    ushort4 a1 = *(const ushort4*)(ybuf + SLAB + s0 + c);
    ushort4 b0 = *(const ushort4*)(ybuf + s1 + c);
    ushort4 b1 = *(const ushort4*)(ybuf + SLAB + s1 + c);
    float4 o;
    o.x = bf2f(a0.x) + bf2f(a1.x) + bf2f(b0.x) + bf2f(b1.x);
    o.y = bf2f(a0.y) + bf2f(a1.y) + bf2f(b0.y) + bf2f(b1.y);
    o.z = bf2f(a0.z) + bf2f(a1.z) + bf2f(b0.z) + bf2f(b1.z);
    o.w = bf2f(a0.w) + bf2f(a1.w) + bf2f(b0.w) + bf2f(b1.w);
    *(float4*)(out + (size_t)t * DIM_ + c) = o;
  }
}

// ---------------- launch ----------------

extern "C" void kernel_launch(void* const* d_in, const int* in_sizes, int n_in,
                              void* d_out, int out_size, void* d_ws, size_t ws_size,
                              hipStream_t stream) {
  const float* x  = (const float*)d_in[0];
  const float* rw = (const float*)d_in[1];
  const float* rb = (const float*)d_in[2];
  const float* W1 = (const float*)d_in[3];
  const float* b1 = (const float*)d_in[4];
  const float* W2 = (const float*)d_in[5];
  const float* b2 = (const float*)d_in[6];
  float* out = (float*)d_out;

  char* ws = (char*)d_ws;
  int*    counts   = (int*)ws;
  int*    btok     = (int*)(ws + 256);
  float*  bw       = (float*)(ws + 256 + 262144);
  int*    tokrec   = (int*)(ws + 256 + 524288);
  int*    gcnt     = (int*)(ws + 655360);
  int2*   te_l     = (int2*)(ws + 720896);
  float2* tw       = (float2*)(ws + 786432);
  u16* xb  = (u16*)(ws + (1u << 20));
  u16* w1t = xb  + (size_t)NTOK * DIM_;
  u16* w2t = w1t + (size_t)E_ * H2_ * DIM_;
  u16* hb  = w2t + (size_t)E_ * DIM_ * HID_;
  u16* ybuf = w1t;  // 2 slabs x 32 MB aliasing w1t (dead after gemm1)

  prep<<<13312, 256, 0, stream>>>(W1, w1t, W2, w2t, x, rw, rb, xb, gcnt, te_l, tw);
  routerBC<<<32, 256, 0, stream>>>(gcnt, counts, te_l, tw, btok, bw, tokrec);

  gemm1<<<16384, 256, 0, stream>>>(xb, w1t, b1, counts, btok, hb);
  gemm2<<<8192, 256, 0, stream>>>(hb, w2t, b2, counts, bw, ybuf);
  combine<<<NTOK / 4, 256, 0, stream>>>(ybuf, tokrec, counts, out);
}